// Round 14
// baseline (479.030 us; speedup 1.0000x reference)
//
#include <hip/hip_runtime.h>
#include <hip/hip_bf16.h>
#include <math.h>

namespace {

constexpr int B  = 4;
constexpr int N  = 2048;
constexpr int F0 = 6;
constexpr int F  = 64;
constexpr int DK = 16;
constexpr float EPS = 1e-5f;
constexpr int NCH = 8;      // n-chunks
constexpr int MT  = N / 64; // 32 m-tiles (64 rows)
constexpr int NGRP = B * MT;  // 128 (b,mtile) groups

typedef float fx4 __attribute__((ext_vector_type(4)));
typedef __attribute__((ext_vector_type(8)))  short bf16x8;
typedef __attribute__((ext_vector_type(4)))  short bf16x4;
typedef __attribute__((ext_vector_type(16))) float f32x16;

__device__ inline short f2bf(float x, float* xr) {
  __hip_bfloat16 h = __float2bfloat16(x);
  *xr = __bfloat162float(h);
  short s; __builtin_memcpy(&s, &h, 2);
  return s;
}
__device__ inline short f2bf(float x) {
  __hip_bfloat16 h = __float2bfloat16(x);
  short s; __builtin_memcpy(&s, &h, 2);
  return s;
}

// ---------------- weight-folding GEMMs -> bf16 operands (unchanged from R12
// except NORM stats now come from 32 per-m-tile partials per row) ----------------
template<int FIN, bool NORM>
__global__ __launch_bounds__(256) void k_wx(const float* __restrict__ X,     // (B,FIN,N)
                                            const float* __restrict__ sigma, // layer0 only
                                            const float* __restrict__ ssum,  // (B*F,32)
                                            const float* __restrict__ ssq,
                                            const float* __restrict__ Wc,    // (64,2*FIN)
                                            const float* __restrict__ Wr,    // (64,FIN)
                                            const float* __restrict__ Ap,    // (DK,FIN) or null
                                            float* __restrict__ T,           // (B,2,64,N)
                                            short* __restrict__ Tbf,         // (B,64,N) bf16
                                            short* __restrict__ projbf,      // (B,DK,N) bf16
                                            float* __restrict__ sqnb) {      // (B,N)
  int z = blockIdx.z, b = blockIdx.y, n0 = blockIdx.x * 64;
  int t = threadIdx.x, n = t & 63, og = t >> 6;
  __shared__ float xS[64][FIN + 1];
  __shared__ __align__(16) float wT[FIN][68];
  __shared__ float mnS[64], rsS[64];
  __shared__ float sp[4][64];
  for (int e = t; e < FIN * 64; e += 256) {
    int f = e >> 6, nn = e & 63;
    xS[nn][f] = X[((size_t)b * FIN + f) * N + n0 + nn];
  }
  bool l0proj = (z == 3 && Ap == nullptr);
  if (!l0proj) {
    const float* base; int ld, off, OUT;
    if (z == 0)      { base = Wc; ld = 2 * FIN; off = 0;   OUT = 64; }
    else if (z == 1) { base = Wc; ld = 2 * FIN; off = FIN; OUT = 64; }
    else if (z == 2) { base = Wr; ld = FIN;     off = 0;   OUT = 64; }
    else             { base = Ap; ld = FIN;     off = 0;   OUT = DK; }
    for (int e = t; e < OUT * FIN; e += 256) {
      int o = e / FIN, f = e - o * FIN;
      wT[f][o] = base[(size_t)o * ld + off + f];
    }
  }
  if (NORM && z < 3 && t < 64) {
    int row = b * FIN + t;
    const fx4* s4 = (const fx4*)(ssum + (size_t)row * MT);
    const fx4* q4 = (const fx4*)(ssq + (size_t)row * MT);
    float S = 0.f, Q = 0.f;
#pragma unroll
    for (int p = 0; p < MT / 4; ++p) {
      fx4 v = s4[p]; S += v[0] + v[1] + v[2] + v[3];
      fx4 u = q4[p]; Q += u[0] + u[1] + u[2] + u[3];
    }
    float mn = S / (float)N;
    mnS[t] = mn;
    rsS[t] = rsqrtf(Q / (float)N - mn * mn + EPS);
  }
  __syncthreads();
  if (z < 3) {
    float cacc[16] = {};
#pragma unroll 4
    for (int f = 0; f < FIN; ++f) {
      float x = xS[n][f];
      if (NORM) x = (x - mnS[f]) * rsS[f];
      fx4 w0 = *(const fx4*)&wT[f][og * 16 + 0];
      fx4 w1 = *(const fx4*)&wT[f][og * 16 + 4];
      fx4 w2 = *(const fx4*)&wT[f][og * 16 + 8];
      fx4 w3 = *(const fx4*)&wT[f][og * 16 + 12];
#pragma unroll
      for (int k = 0; k < 4; ++k) {
        cacc[k + 0]  = fmaf(w0[k], x, cacc[k + 0]);
        cacc[k + 4]  = fmaf(w1[k], x, cacc[k + 4]);
        cacc[k + 8]  = fmaf(w2[k], x, cacc[k + 8]);
        cacc[k + 12] = fmaf(w3[k], x, cacc[k + 12]);
      }
    }
    if (z == 1) {
#pragma unroll
      for (int k = 0; k < 16; ++k)
        Tbf[((size_t)b * 64 + og * 16 + k) * N + n0 + n] = f2bf(cacc[k]);
    } else {
      int sl = (z == 0) ? 0 : 1;
#pragma unroll
      for (int k = 0; k < 16; ++k)
        T[(((size_t)b * 2 + sl) * 64 + og * 16 + k) * N + n0 + n] = cacc[k];
    }
  } else {
    float r[4];
    if (Ap != nullptr) {
      float cacc[4] = {};
#pragma unroll 4
      for (int f = 0; f < FIN; ++f) {
        float x = xS[n][f];
        fx4 w0 = *(const fx4*)&wT[f][og * 4];
#pragma unroll
        for (int k = 0; k < 4; ++k) cacc[k] = fmaf(w0[k], x, cacc[k]);
      }
#pragma unroll
      for (int k = 0; k < 4; ++k) {
        short hs = f2bf(cacc[k], &r[k]);
        projbf[((size_t)b * DK + og * 4 + k) * N + n0 + n] = hs;
      }
    } else {
      float inv = 1.f / sigma[0];
#pragma unroll
      for (int k = 0; k < 4; ++k) {
        int d = og * 4 + k;
        float v = (d < F0) ? xS[n][d] * inv : 0.f;
        short hs = f2bf(v, &r[k]);
        projbf[((size_t)b * DK + d) * N + n0 + n] = hs;
      }
    }
    float s = 0.f;
#pragma unroll
    for (int k = 0; k < 4; ++k) s = fmaf(r[k], r[k], s);
    sp[og][n] = s;
    __syncthreads();
    if (t < 64) sqnb[(size_t)b * N + n0 + t] = sp[0][t] + sp[1][t] + sp[2][t] + sp[3][t];
  }
}

// ---------------- adjacency+deg+PV (R12 main loop) + fused last-block ep tail ----------------
// Grid 1024 = 8 xcd × 8 ch × 16 lc. All 8 ch-blocks of group g=(b,mtile) share an
// XCD (i%8 == xcd): pdmsg partials stay in that XCD's L2; tail (8th arrival) does
// the gopconv epilogue for the group's 64-n slice. Layer-2 tail also runs readout.
template<bool LAST>
__global__ __launch_bounds__(256, 4) void k_adjep(const short* __restrict__ projbf,
                                                  const float* __restrict__ sqnb,
                                                  const short* __restrict__ Tbf,
                                                  const float* __restrict__ T,
                                                  const float* __restrict__ bias,
                                                  const float* __restrict__ bres,
                                                  float* __restrict__ emb,    // out (B,64,N)
                                                  float* __restrict__ pdmsg,  // (NCH,B,F,N)
                                                  float* __restrict__ pdeg,   // (NCH,B,N)
                                                  float* __restrict__ ssum,   // (B*F,MT)
                                                  float* __restrict__ ssq,
                                                  int* __restrict__ cnt,      // [NGRP]
                                                  int* __restrict__ gcnt,
                                                  const float* __restrict__ fw,
                                                  const float* __restrict__ fb,
                                                  float* __restrict__ outF) {
  int i = blockIdx.x;
  int xcd = i & 7;
  int r0 = i >> 3;
  int ch = r0 & 7;
  int lc = r0 >> 3;              // 0..15
  int g = xcd * 16 + lc;         // group 0..127, same-XCD across ch
  int b = g >> 5, mtile = g & 31;
  int M0 = mtile * 64;
  int n0 = ch * (N / NCH);       // 256-n chunk
  int combo = ch * B + b;

  int t = threadIdx.x;
  int w = t >> 6, l = t & 63;
  int l31 = l & 31, lh = l >> 5;
  int mq = w & 1, nq = w >> 1;
  int fq = w & 1, mq2 = w >> 1;

  const short* pb = projbf + (size_t)b * DK * N;
  const short* vb = Tbf + (size_t)b * F * N;
  const float* sq = sqnb + (size_t)b * N;

  __shared__ __align__(16) short adjT[2][64][68];
  __shared__ __align__(16) short vS[2][64][68];
  __shared__ float sqmS[64];
  __shared__ float degS[2][64];
  __shared__ int flagS;

  bf16x8 afrag;
  {
    int am = l31 + 32 * mq;
#pragma unroll
    for (int i2 = 0; i2 < 8; ++i2)
      afrag[i2] = pb[(size_t)(lh * 8 + i2) * N + M0 + am];
  }
  if (t < 64) sqmS[t] = sq[M0 + t];
  __syncthreads();
  float sqmr[16];
#pragma unroll
  for (int r = 0; r < 16; ++r)
    sqmr[r] = sqmS[(r & 3) + 8 * (r >> 2) + 4 * lh + 32 * mq];

  f32x16 acc;
#pragma unroll
  for (int r = 0; r < 16; ++r) acc[r] = 0.f;
  float pdm[16];
#pragma unroll
  for (int r = 0; r < 16; ++r) pdm[r] = 0.f;

  int buf = 0;
  for (int nt = 0; nt < N / NCH; nt += 64) {
    bf16x8 bfrag;
    int bn = l31 + 32 * nq;
#pragma unroll
    for (int i2 = 0; i2 < 8; ++i2)
      bfrag[i2] = pb[(size_t)(lh * 8 + i2) * N + n0 + nt + bn];
    float sqn_v = sq[n0 + nt + bn];
    {
      int f = t >> 2, nb16 = (t & 3) * 16;
#pragma unroll
      for (int jj = 0; jj < 4; ++jj) {
        *(bf16x4*)&vS[buf][f][nb16 + 4 * jj] =
            *(const bf16x4*)&vb[(size_t)f * N + n0 + nt + nb16 + 4 * jj];
      }
    }
    f32x16 gz;
#pragma unroll
    for (int r = 0; r < 16; ++r) gz[r] = 0.f;
    f32x16 gg = __builtin_amdgcn_mfma_f32_32x32x16_bf16(afrag, bfrag, gz, 0, 0, 0);
#pragma unroll
    for (int r = 0; r < 16; ++r) {
      int m = (r & 3) + 8 * (r >> 2) + 4 * lh + 32 * mq;
      float dist = fmaxf(sqmr[r] + sqn_v - 2.f * gg[r], 0.f);
      float a = __expf(-dist);
      pdm[r] += a;
      adjT[buf][m][bn] = f2bf(a);
    }
    __syncthreads();
#pragma unroll
    for (int kk = 0; kk < 4; ++kk) {
      int nb = kk * 16 + lh * 8;
      int fA = l31 + 32 * fq;
      int mB = l31 + 32 * mq2;
      bf16x4 alo = *(const bf16x4*)&vS[buf][fA][nb];
      bf16x4 ahi = *(const bf16x4*)&vS[buf][fA][nb + 4];
      bf16x4 blo = *(const bf16x4*)&adjT[buf][mB][nb];
      bf16x4 bhi = *(const bf16x4*)&adjT[buf][mB][nb + 4];
      bf16x8 af2, bf2;
#pragma unroll
      for (int i2 = 0; i2 < 4; ++i2) {
        af2[i2] = alo[i2]; af2[i2 + 4] = ahi[i2];
        bf2[i2] = blo[i2]; bf2[i2 + 4] = bhi[i2];
      }
      acc = __builtin_amdgcn_mfma_f32_32x32x16_bf16(af2, bf2, acc, 0, 0, 0);
    }
    buf ^= 1;
  }
#pragma unroll
  for (int r = 0; r < 16; ++r) {
    pdm[r] += __shfl_xor(pdm[r], 1);
    pdm[r] += __shfl_xor(pdm[r], 2);
    pdm[r] += __shfl_xor(pdm[r], 4);
    pdm[r] += __shfl_xor(pdm[r], 8);
    pdm[r] += __shfl_xor(pdm[r], 16);
  }
  if (l31 == 0) {
#pragma unroll
    for (int r = 0; r < 16; ++r)
      degS[nq][(r & 3) + 8 * (r >> 2) + 4 * lh + 32 * mq] = pdm[r];
  }
  __syncthreads();
  if (t < 64) {
    float s = degS[0][t] + degS[1][t];
    pdeg[(size_t)combo * N + M0 + t] = s;   // plain: stays in this XCD's L2
  }
  {
    float* pdm_g = pdmsg + (size_t)combo * F * N;
    int m_out = l31 + 32 * mq2;
#pragma unroll
    for (int r = 0; r < 16; ++r) {
      int f_r = (r & 3) + 8 * (r >> 2) + 4 * lh + 32 * fq;
      pdm_g[(size_t)f_r * N + M0 + m_out] = acc[r];
    }
  }

  // ---- group rendezvous: 8th arrival runs the ep tail for (b, mtile) ----
  __threadfence();
  __syncthreads();
  if (t == 0) {
    int old = atomicAdd(&cnt[g], 1);
    flagS = (old == NCH - 1);
    if (old == NCH - 1) atomicExch(&cnt[g], 0);  // self-clean for next layer
  }
  __syncthreads();
  if (!flagS) return;
  __threadfence();  // acquire: pdmsg/pdeg of all 8 ch-blocks (same XCD L2)

  {
    int col = t & 15;        // fx4 col within 64-n slice
    int orow = t >> 4;       // 0..15
    int colBase = (M0 >> 2) + col;
    const fx4* T0 = (const fx4*)(T + ((size_t)b * 2 + 0) * 64 * N);
    const fx4* T2 = (const fx4*)(T + ((size_t)b * 2 + 1) * 64 * N);
    fx4 dg = {0.f, 0.f, 0.f, 0.f};
#pragma unroll
    for (int c = 0; c < NCH; ++c)
      dg += ((const fx4*)pdeg)[(((size_t)(c * B + b)) * N >> 2) + colBase];
#pragma unroll
    for (int pass = 0; pass < 4; ++pass) {
      int o = pass * 16 + orow;
      fx4 dm = {0.f, 0.f, 0.f, 0.f};
#pragma unroll
      for (int c = 0; c < NCH; ++c)
        dm += ((const fx4*)pdmsg)[((((size_t)(c * B + b)) * 64 + o) * N >> 2) + colBase];
      fx4 t0v = T0[((size_t)o * N >> 2) + colBase];
      fx4 t2v = T2[((size_t)o * N >> 2) + colBase];
      float bi = bias[o], br = bres[o];
      fx4 ov;
#pragma unroll
      for (int j = 0; j < 4; ++j)
        ov[j] = fmaxf(dm[j] + t0v[j] * dg[j] + bi, 0.f) + t2v[j] + br;
      if (!LAST)
        ((fx4*)emb)[((((size_t)b * 64 + o)) * N >> 2) + colBase] = ov;
      float ps = ov[0] + ov[1] + ov[2] + ov[3];
      float pq = fmaf(ov[0], ov[0], fmaf(ov[1], ov[1], fmaf(ov[2], ov[2], ov[3] * ov[3])));
      ps += __shfl_xor(ps, 1); pq += __shfl_xor(pq, 1);
      ps += __shfl_xor(ps, 2); pq += __shfl_xor(pq, 2);
      ps += __shfl_xor(ps, 4); pq += __shfl_xor(pq, 4);
      ps += __shfl_xor(ps, 8); pq += __shfl_xor(pq, 8);
      if (col == 0) {
        size_t idx = ((size_t)b * 64 + o) * MT + mtile;
        if (LAST) {
          __hip_atomic_store(&ssum[idx], ps, __ATOMIC_RELAXED, __HIP_MEMORY_SCOPE_AGENT);
        } else {
          ssum[idx] = ps;
          ssq[idx]  = pq;
        }
      }
    }
  }

  if (LAST) {
    // ---- globally-last tail runs the readout ----
    __threadfence();
    __syncthreads();
    if (t == 0) {
      int old = atomicAdd(gcnt, 1);
      flagS = (old == NGRP - 1);
      if (old == NGRP - 1) atomicExch(gcnt, 0);
    }
    __syncthreads();
    if (!flagS) return;
    __threadfence();
    int b2 = t >> 6, l2 = t & 63;
    const float* sp = ssum + ((size_t)b2 * 64 + l2) * MT;
    float po = 0.f;
#pragma unroll
    for (int p = 0; p < MT; ++p)
      po += __hip_atomic_load(&sp[p], __ATOMIC_RELAXED, __HIP_MEMORY_SCOPE_AGENT);
    po /= (float)N;
    float mn = po;
#pragma unroll
    for (int off = 1; off < 64; off <<= 1) mn += __shfl_xor(mn, off);
    mn *= (1.f / 64.f);
    float d = po - mn;
    float var = d * d;
#pragma unroll
    for (int off = 1; off < 64; off <<= 1) var += __shfl_xor(var, off);
    var *= (1.f / 64.f);
    float rs = rsqrtf(var + EPS);
    float lg = d * rs * fw[l2];
#pragma unroll
    for (int off = 1; off < 64; off <<= 1) lg += __shfl_xor(lg, off);
    if (l2 == 0) outF[b2] = 1.f / (1.f + __expf(-(lg + fb[0])));
  }
}

}  // namespace

extern "C" void kernel_launch(void* const* d_in, const int* in_sizes, int n_in,
                              void* d_out, int out_size, void* d_ws, size_t ws_size,
                              hipStream_t stream) {
  const float* emb_in   = (const float*)d_in[0];
  const float* sigma    = (const float*)d_in[1];
  const float* fst_w    = (const float*)d_in[2];
  const float* fst_b    = (const float*)d_in[3];
  const float* fst_wres = (const float*)d_in[4];
  const float* fst_bres = (const float*)d_in[5];
  const float* adj_proj = (const float*)d_in[6];
  const float* w        = (const float*)d_in[7];
  const float* bw       = (const float*)d_in[8];
  const float* wres     = (const float*)d_in[9];
  const float* bres     = (const float*)d_in[10];
  const float* fcl_w    = (const float*)d_in[11];
  const float* fcl_b    = (const float*)d_in[12];

  float* ws = (float*)d_ws;
  float* pdeg  = ws;  ws += (size_t)NCH * B * N;
  float* pdmsg = ws;  ws += (size_t)NCH * B * F * N;
  float* embA  = ws;  ws += (size_t)B * F * N;
  float* embB  = ws;  ws += (size_t)B * F * N;
  float* T     = ws;  ws += 2 * (size_t)B * F * N;
  short* Tbf   = (short*)ws;  ws += (size_t)B * F * N / 2;
  short* projbf = (short*)ws; ws += (size_t)B * DK * N / 2;
  float* sqnb  = ws;  ws += (size_t)B * N;
  float* ssum  = ws;  ws += (size_t)B * F * MT;
  float* ssq   = ws;  ws += (size_t)B * F * MT;
  int* cnt     = (int*)ws;    // [NGRP] group counters + 1 global
  int* gcnt    = cnt + NGRP;

  hipMemsetAsync(cnt, 0, (NGRP + 1) * sizeof(int), stream);

  // ---- layer 0 ----
  k_wx<F0, false><<<dim3(N / 64, B, 4), 256, 0, stream>>>(
      emb_in, sigma, nullptr, nullptr, fst_w, fst_wres, nullptr, T, Tbf, projbf, sqnb);
  k_adjep<false><<<dim3(8 * NCH * 16), 256, 0, stream>>>(
      projbf, sqnb, Tbf, T, fst_b, fst_bres, embA, pdmsg, pdeg, ssum, ssq,
      cnt, gcnt, nullptr, nullptr, nullptr);

  // ---- layer 1 ----
  k_wx<F, true><<<dim3(N / 64, B, 4), 256, 0, stream>>>(
      embA, nullptr, ssum, ssq, w, wres, adj_proj, T, Tbf, projbf, sqnb);
  k_adjep<false><<<dim3(8 * NCH * 16), 256, 0, stream>>>(
      projbf, sqnb, Tbf, T, bw, bres, embB, pdmsg, pdeg, ssum, ssq,
      cnt, gcnt, nullptr, nullptr, nullptr);

  // ---- layer 2 (+fused readout) ----
  k_wx<F, true><<<dim3(N / 64, B, 4), 256, 0, stream>>>(
      embB, nullptr, ssum, ssq, w + (size_t)F * 2 * F, wres + (size_t)F * F,
      adj_proj + (size_t)DK * F, T, Tbf, projbf, sqnb);
  k_adjep<true><<<dim3(8 * NCH * 16), 256, 0, stream>>>(
      projbf, sqnb, Tbf, T, bw + F, bres + F, embA, pdmsg, pdeg, ssum, ssq,
      cnt, gcnt, fcl_w, fcl_b, (float*)d_out);
}

// Round 15
// 107.177 us; speedup vs baseline: 4.4695x; 4.4695x over previous
//
#include <hip/hip_runtime.h>
#include <hip/hip_bf16.h>
#include <math.h>

namespace {

constexpr int B  = 4;
constexpr int N  = 2048;
constexpr int F0 = 6;
constexpr int F  = 64;
constexpr int DK = 16;
constexpr float EPS = 1e-5f;
constexpr int MT   = N / 64;  // m-tiles

typedef float fx4 __attribute__((ext_vector_type(4)));
typedef __attribute__((ext_vector_type(8)))  short bf16x8;
typedef __attribute__((ext_vector_type(4)))  short bf16x4;
typedef __attribute__((ext_vector_type(16))) float f32x16;

__device__ inline short f2bf(float x, float* xr) {
  __hip_bfloat16 h = __float2bfloat16(x);
  *xr = __bfloat162float(h);
  short s; __builtin_memcpy(&s, &h, 2);
  return s;
}
__device__ inline short f2bf(float x) {
  __hip_bfloat16 h = __float2bfloat16(x);
  short s; __builtin_memcpy(&s, &h, 2);
  return s;
}

// ---------------- weight-folding GEMMs -> bf16 operands for adjmsg ----------------
// z==0: T slice0 = W1·norm(X) (fp32)   z==1: Tbf = bf16(W2·norm(X))
// z==2: T slice1 = Wres·norm(X) (fp32) z==3: projbf = bf16(Ap·X) + sqnb (rounded-val norms)
//        (layer 0: projbf = bf16(X/sigma) zero-padded to DK rows)
template<int FIN, bool NORM>
__global__ __launch_bounds__(256) void k_wx(const float* __restrict__ X,     // (B,FIN,N)
                                            const float* __restrict__ sigma, // layer0 only
                                            const float* __restrict__ ssum,  // (2*B*F) ep partials
                                            const float* __restrict__ ssq,
                                            const float* __restrict__ Wc,    // (64,2*FIN)
                                            const float* __restrict__ Wr,    // (64,FIN)
                                            const float* __restrict__ Ap,    // (DK,FIN) or null
                                            float* __restrict__ T,           // (B,2,64,N)
                                            short* __restrict__ Tbf,         // (B,64,N) bf16
                                            short* __restrict__ projbf,      // (B,DK,N) bf16
                                            float* __restrict__ sqnb) {      // (B,N)
  int z = blockIdx.z, b = blockIdx.y, n0 = blockIdx.x * 64;
  int t = threadIdx.x, n = t & 63, og = t >> 6;
  __shared__ float xS[64][FIN + 1];
  __shared__ __align__(16) float wT[FIN][68];
  __shared__ float mnS[64], rsS[64];
  __shared__ float sp[4][64];
  for (int e = t; e < FIN * 64; e += 256) {
    int f = e >> 6, nn = e & 63;
    xS[nn][f] = X[((size_t)b * FIN + f) * N + n0 + nn];
  }
  bool l0proj = (z == 3 && Ap == nullptr);
  if (!l0proj) {
    const float* base; int ld, off, OUT;
    if (z == 0)      { base = Wc; ld = 2 * FIN; off = 0;   OUT = 64; }
    else if (z == 1) { base = Wc; ld = 2 * FIN; off = FIN; OUT = 64; }
    else if (z == 2) { base = Wr; ld = FIN;     off = 0;   OUT = 64; }
    else             { base = Ap; ld = FIN;     off = 0;   OUT = DK; }
    for (int e = t; e < OUT * FIN; e += 256) {
      int o = e / FIN, f = e - o * FIN;
      wT[f][o] = base[(size_t)o * ld + off + f];
    }
  }
  if (NORM && z < 3 && t < 64) {  // mean/rstd from ep partial sums (2 halves/row)
    int row = b * FIN + t;
    float S = ssum[2 * row] + ssum[2 * row + 1];
    float Q = ssq[2 * row] + ssq[2 * row + 1];
    float mn = S / (float)N;
    mnS[t] = mn;
    rsS[t] = rsqrtf(Q / (float)N - mn * mn + EPS);
  }
  __syncthreads();
  if (z < 3) {
    float cacc[16] = {};
#pragma unroll 4
    for (int f = 0; f < FIN; ++f) {
      float x = xS[n][f];
      if (NORM) x = (x - mnS[f]) * rsS[f];
      fx4 w0 = *(const fx4*)&wT[f][og * 16 + 0];
      fx4 w1 = *(const fx4*)&wT[f][og * 16 + 4];
      fx4 w2 = *(const fx4*)&wT[f][og * 16 + 8];
      fx4 w3 = *(const fx4*)&wT[f][og * 16 + 12];
#pragma unroll
      for (int k = 0; k < 4; ++k) {
        cacc[k + 0]  = fmaf(w0[k], x, cacc[k + 0]);
        cacc[k + 4]  = fmaf(w1[k], x, cacc[k + 4]);
        cacc[k + 8]  = fmaf(w2[k], x, cacc[k + 8]);
        cacc[k + 12] = fmaf(w3[k], x, cacc[k + 12]);
      }
    }
    if (z == 1) {
#pragma unroll
      for (int k = 0; k < 16; ++k)
        Tbf[((size_t)b * 64 + og * 16 + k) * N + n0 + n] = f2bf(cacc[k]);
    } else {
      int sl = (z == 0) ? 0 : 1;
#pragma unroll
      for (int k = 0; k < 16; ++k)
        T[(((size_t)b * 2 + sl) * 64 + og * 16 + k) * N + n0 + n] = cacc[k];
    }
  } else {
    // proj path: compute 4 rows (d = og*4+k), round to bf16, write + sqnorm of rounded
    float r[4];
    if (Ap != nullptr) {
      float cacc[4] = {};
#pragma unroll 4
      for (int f = 0; f < FIN; ++f) {
        float x = xS[n][f];
        fx4 w0 = *(const fx4*)&wT[f][og * 4];
#pragma unroll
        for (int k = 0; k < 4; ++k) cacc[k] = fmaf(w0[k], x, cacc[k]);
      }
#pragma unroll
      for (int k = 0; k < 4; ++k) {
        short hs = f2bf(cacc[k], &r[k]);
        projbf[((size_t)b * DK + og * 4 + k) * N + n0 + n] = hs;
      }
    } else {  // layer 0: scaled + zero-padded
      float inv = 1.f / sigma[0];
#pragma unroll
      for (int k = 0; k < 4; ++k) {
        int d = og * 4 + k;
        float v = (d < F0) ? xS[n][d] * inv : 0.f;
        short hs = f2bf(v, &r[k]);
        projbf[((size_t)b * DK + d) * N + n0 + n] = hs;
      }
    }
    float s = 0.f;
#pragma unroll
    for (int k = 0; k < 4; ++k) s = fmaf(r[k], r[k], s);
    sp[og][n] = s;
    __syncthreads();
    if (t < 64) sqnb[(size_t)b * N + n0 + t] = sp[0][t] + sp[1][t] + sp[2][t] + sp[3][t];
  }
}

// ---------------- adjacency+deg+PV via bf16 MFMA; bf16 operands, precomputed norms ----------------
__global__ __launch_bounds__(256, 4) void k_adjmsg(const short* __restrict__ projbf,
                                                   const float* __restrict__ sqnb,
                                                   const short* __restrict__ Tbf,
                                                   float* __restrict__ pdmsg,  // (nch,B,F,N)
                                                   float* __restrict__ pdeg,   // (nch,B,N)
                                                   int nch, int cpx) {
  const int NCb = N / nch;
  int i = blockIdx.x;
  int xcd = i & 7;
  int j = i >> 3;
  int lc = j / MT;
  int mtile = j - lc * MT;
  int combo = xcd * cpx + lc;  // bijective XCD swizzle
  int ch = combo >> 2;
  int b  = combo & 3;
  int M0 = mtile * 64;
  int n0 = ch * NCb;

  int t = threadIdx.x;
  int w = t >> 6, l = t & 63;
  int l31 = l & 31, lh = l >> 5;
  int mq = w & 1, nq = w >> 1;
  int fq = w & 1, mq2 = w >> 1;

  const short* pb = projbf + (size_t)b * DK * N;
  const short* vb = Tbf + (size_t)b * F * N;   // bf16 W2·V
  const float* sq = sqnb + (size_t)b * N;

  __shared__ __align__(16) short adjT[2][64][68];
  __shared__ __align__(16) short vS[2][64][68];
  __shared__ float sqmS[64];
  __shared__ float degS[2][64];

  // A-fragment: direct bf16 loads (no cvt); sqm staged from precomputed norms
  bf16x8 afrag;
  {
    int am = l31 + 32 * mq;
#pragma unroll
    for (int i2 = 0; i2 < 8; ++i2)
      afrag[i2] = pb[(size_t)(lh * 8 + i2) * N + M0 + am];
  }
  if (t < 64) sqmS[t] = sq[M0 + t];
  __syncthreads();
  float sqmr[16];
#pragma unroll
  for (int r = 0; r < 16; ++r)
    sqmr[r] = sqmS[(r & 3) + 8 * (r >> 2) + 4 * lh + 32 * mq];

  f32x16 acc;
#pragma unroll
  for (int r = 0; r < 16; ++r) acc[r] = 0.f;
  float pdm[16];
#pragma unroll
  for (int r = 0; r < 16; ++r) pdm[r] = 0.f;

  int buf = 0;
  for (int nt = 0; nt < NCb; nt += 64) {
    // B-fragment + its node-norm, direct from global
    bf16x8 bfrag;
    int bn = l31 + 32 * nq;
#pragma unroll
    for (int i2 = 0; i2 < 8; ++i2)
      bfrag[i2] = pb[(size_t)(lh * 8 + i2) * N + n0 + nt + bn];
    float sqn_v = sq[n0 + nt + bn];
    {  // stage V: raw bf16 copy (no cvt), 32B/thread
      int f = t >> 2, nb16 = (t & 3) * 16;
#pragma unroll
      for (int jj = 0; jj < 4; ++jj) {
        *(bf16x4*)&vS[buf][f][nb16 + 4 * jj] =
            *(const bf16x4*)&vb[(size_t)f * N + n0 + nt + nb16 + 4 * jj];
      }
    }
    // gram via MFMA + exp -> adjT[buf]
    f32x16 gz;
#pragma unroll
    for (int r = 0; r < 16; ++r) gz[r] = 0.f;
    f32x16 g = __builtin_amdgcn_mfma_f32_32x32x16_bf16(afrag, bfrag, gz, 0, 0, 0);
#pragma unroll
    for (int r = 0; r < 16; ++r) {
      int m = (r & 3) + 8 * (r >> 2) + 4 * lh + 32 * mq;
      float dist = fmaxf(sqmr[r] + sqn_v - 2.f * g[r], 0.f);
      float a = __expf(-dist);
      pdm[r] += a;
      adjT[buf][m][bn] = f2bf(a);
    }
    __syncthreads();  // adjT[buf]/vS[buf] ready
    // PV via MFMA: acc[f][m] += sum_n V[f][n] * adj[m][n]
#pragma unroll
    for (int kk = 0; kk < 4; ++kk) {
      int nb = kk * 16 + lh * 8;
      int fA = l31 + 32 * fq;
      int mB = l31 + 32 * mq2;
      bf16x4 alo = *(const bf16x4*)&vS[buf][fA][nb];
      bf16x4 ahi = *(const bf16x4*)&vS[buf][fA][nb + 4];
      bf16x4 blo = *(const bf16x4*)&adjT[buf][mB][nb];
      bf16x4 bhi = *(const bf16x4*)&adjT[buf][mB][nb + 4];
      bf16x8 af2, bf2;
#pragma unroll
      for (int i2 = 0; i2 < 4; ++i2) {
        af2[i2] = alo[i2]; af2[i2 + 4] = ahi[i2];
        bf2[i2] = blo[i2]; bf2[i2 + 4] = bhi[i2];
      }
      acc = __builtin_amdgcn_mfma_f32_32x32x16_bf16(af2, bf2, acc, 0, 0, 0);
    }
    buf ^= 1;
  }
#pragma unroll
  for (int r = 0; r < 16; ++r) {
    pdm[r] += __shfl_xor(pdm[r], 1);
    pdm[r] += __shfl_xor(pdm[r], 2);
    pdm[r] += __shfl_xor(pdm[r], 4);
    pdm[r] += __shfl_xor(pdm[r], 8);
    pdm[r] += __shfl_xor(pdm[r], 16);
  }
  if (l31 == 0) {
#pragma unroll
    for (int r = 0; r < 16; ++r)
      degS[nq][(r & 3) + 8 * (r >> 2) + 4 * lh + 32 * mq] = pdm[r];
  }
  __syncthreads();
  if (t < 64) {
    float s = degS[0][t] + degS[1][t];
    __builtin_nontemporal_store(s, &pdeg[(size_t)combo * N + M0 + t]);
  }
  float* pdm_g = pdmsg + (size_t)combo * F * N;
  int m_out = l31 + 32 * mq2;
#pragma unroll
  for (int r = 0; r < 16; ++r) {
    int f_r = (r & 3) + 8 * (r >> 2) + 4 * lh + 32 * fq;
    __builtin_nontemporal_store(acc[r], &pdm_g[(size_t)f_r * N + M0 + m_out]);
  }
}

// ---------------- fused chunk-combine + epilogue + row-stat partials ----------------
template<int CH>
__global__ __launch_bounds__(256) void k_ep(const float* __restrict__ pdmsg,
                                            const float* __restrict__ pdeg,
                                            const float* __restrict__ T,   // (B,2,64,N)
                                            const float* __restrict__ bias,
                                            const float* __restrict__ bres,
                                            float* __restrict__ out,
                                            float* __restrict__ ssum,   // (2*B*F)
                                            float* __restrict__ ssq) {  // (2*B*F)
  int t = threadIdx.x;
  int idx = blockIdx.x * 256 + t;  // fx4 units, total B*F*N/4
  int row = idx >> 9;              // N/4 = 512
  int c4 = idx & 511;
  int o = row & 63, b = row >> 6;
  fx4 dm = {0.f, 0.f, 0.f, 0.f};
  fx4 dg = {0.f, 0.f, 0.f, 0.f};
#pragma unroll
  for (int c = 0; c < CH; ++c) {
    dm += __builtin_nontemporal_load(&((const fx4*)pdmsg)[(((size_t)c * B + b) * 64 + o) * 512 + c4]);
    dg += ((const fx4*)pdeg)[((size_t)c * B + b) * 512 + c4];
  }
  fx4 t0 = ((const fx4*)T)[(((size_t)b * 2 + 0) * 64 + o) * 512 + c4];
  fx4 t2 = ((const fx4*)T)[(((size_t)b * 2 + 1) * 64 + o) * 512 + c4];
  float bi = bias[o], br = bres[o];
  fx4 r = dm + t0 * dg;
  fx4 ov;
#pragma unroll
  for (int j = 0; j < 4; ++j) ov[j] = fmaxf(r[j] + bi, 0.f) + t2[j] + br;
  ((fx4*)out)[((size_t)b * 64 + o) * 512 + c4] = ov;
  float ps = ov[0] + ov[1] + ov[2] + ov[3];
  float pq = fmaf(ov[0], ov[0], fmaf(ov[1], ov[1], fmaf(ov[2], ov[2], ov[3] * ov[3])));
#pragma unroll
  for (int off = 1; off < 64; off <<= 1) {
    ps += __shfl_xor(ps, off);
    pq += __shfl_xor(pq, off);
  }
  __shared__ float r1[4], r2[4];
  if ((t & 63) == 0) { r1[t >> 6] = ps; r2[t >> 6] = pq; }
  __syncthreads();
  if (t == 0) {
    ssum[blockIdx.x] = r1[0] + r1[1] + r1[2] + r1[3];
    ssq[blockIdx.x]  = r2[0] + r2[1] + r2[2] + r2[3];
  }
}

// ---------------- readout from ep partials ----------------
__global__ __launch_bounds__(256) void k_readout(const float* __restrict__ ssum,
                                                 const float* __restrict__ fw,
                                                 const float* __restrict__ fb,
                                                 float* __restrict__ out) {
  int t = threadIdx.x, b = t >> 6, l = t & 63;
  int row = b * 64 + l;
  float po = (ssum[2 * row] + ssum[2 * row + 1]) / (float)N;
  float mn = po;
#pragma unroll
  for (int off = 1; off < 64; off <<= 1) mn += __shfl_xor(mn, off);
  mn *= (1.f / 64.f);
  float d = po - mn;
  float var = d * d;
#pragma unroll
  for (int off = 1; off < 64; off <<= 1) var += __shfl_xor(var, off);
  var *= (1.f / 64.f);
  float rs = rsqrtf(var + EPS);
  float lg = d * rs * fw[l];
#pragma unroll
  for (int off = 1; off < 64; off <<= 1) lg += __shfl_xor(lg, off);
  if (l == 0) out[b] = 1.f / (1.f + __expf(-(lg + fb[0])));
}

}  // namespace

extern "C" void kernel_launch(void* const* d_in, const int* in_sizes, int n_in,
                              void* d_out, int out_size, void* d_ws, size_t ws_size,
                              hipStream_t stream) {
  const float* emb_in   = (const float*)d_in[0];
  const float* sigma    = (const float*)d_in[1];
  const float* fst_w    = (const float*)d_in[2];
  const float* fst_b    = (const float*)d_in[3];
  const float* fst_wres = (const float*)d_in[4];
  const float* fst_bres = (const float*)d_in[5];
  const float* adj_proj = (const float*)d_in[6];
  const float* w        = (const float*)d_in[7];
  const float* bw       = (const float*)d_in[8];
  const float* wres     = (const float*)d_in[9];
  const float* bres     = (const float*)d_in[10];
  const float* fcl_w    = (const float*)d_in[11];
  const float* fcl_b    = (const float*)d_in[12];

  auto need_bytes = [](int nch) -> size_t {
    size_t f = 0;
    f += (size_t)nch * B * N;           // pdeg
    f += (size_t)nch * B * F * N;       // pdmsg
    f += 2 * (size_t)B * F * N;         // embA, embB
    f += 2 * (size_t)B * F * N;         // T (2 slices)
    f += (size_t)B * F * N / 2;         // Tbf (bf16)
    f += (size_t)B * DK * N / 2;        // projbf (bf16)
    f += (size_t)B * N;                 // sqnb
    f += 4 * (size_t)B * F;             // ssum, ssq
    return f * 4;
  };
  int nch = (ws_size >= need_bytes(8)) ? 8 : 4;
  int cpx = nch * B / 8;

  float* ws = (float*)d_ws;
  float* pdeg  = ws;  ws += (size_t)nch * B * N;
  float* pdmsg = ws;  ws += (size_t)nch * B * F * N;
  float* embA  = ws;  ws += (size_t)B * F * N;
  float* embB  = ws;  ws += (size_t)B * F * N;
  float* T     = ws;  ws += 2 * (size_t)B * F * N;
  short* Tbf   = (short*)ws;  ws += (size_t)B * F * N / 2;
  short* projbf = (short*)ws; ws += (size_t)B * DK * N / 2;
  float* sqnb  = ws;  ws += (size_t)B * N;
  float* ssum  = ws;  ws += 2 * (size_t)B * F;
  float* ssq   = ws;  ws += 2 * (size_t)B * F;

  constexpr int EPB = (B * F * N / 4) / 256;  // 512 blocks; block = half output row

  // ---- layer 0 ----
  k_wx<F0, false><<<dim3(N / 64, B, 4), 256, 0, stream>>>(
      emb_in, sigma, nullptr, nullptr, fst_w, fst_wres, nullptr, T, Tbf, projbf, sqnb);
  k_adjmsg<<<dim3(MT * nch * B), 256, 0, stream>>>(projbf, sqnb, Tbf, pdmsg, pdeg, nch, cpx);
  if (nch == 8)
    k_ep<8><<<dim3(EPB), 256, 0, stream>>>(pdmsg, pdeg, T, fst_b, fst_bres, embA, ssum, ssq);
  else
    k_ep<4><<<dim3(EPB), 256, 0, stream>>>(pdmsg, pdeg, T, fst_b, fst_bres, embA, ssum, ssq);

  // ---- layers 1..2 ----
  const float* src = embA;
  float* dst = embB;
  for (int i = 0; i < 2; ++i) {
    k_wx<F, true><<<dim3(N / 64, B, 4), 256, 0, stream>>>(
        src, nullptr, ssum, ssq, w + (size_t)i * F * 2 * F, wres + (size_t)i * F * F,
        adj_proj + (size_t)i * DK * F, T, Tbf, projbf, sqnb);
    k_adjmsg<<<dim3(MT * nch * B), 256, 0, stream>>>(projbf, sqnb, Tbf, pdmsg, pdeg, nch, cpx);
    if (nch == 8)
      k_ep<8><<<dim3(EPB), 256, 0, stream>>>(pdmsg, pdeg, T, bw + (size_t)i * F,
                                             bres + (size_t)i * F, dst, ssum, ssq);
    else
      k_ep<4><<<dim3(EPB), 256, 0, stream>>>(pdmsg, pdeg, T, bw + (size_t)i * F,
                                             bres + (size_t)i * F, dst, ssum, ssq);
    float* tmp = (float*)src;
    src = dst;
    dst = tmp;
  }

  k_readout<<<dim3(1), 256, 0, stream>>>(ssum, fcl_w, fcl_b, (float*)d_out);
}

// Round 16
// 105.528 us; speedup vs baseline: 4.5394x; 1.0156x over previous
//
#include <hip/hip_runtime.h>
#include <hip/hip_bf16.h>
#include <math.h>

namespace {

constexpr int B  = 4;
constexpr int N  = 2048;
constexpr int F0 = 6;
constexpr int F  = 64;
constexpr int DK = 16;
constexpr float EPS = 1e-5f;
constexpr int MT   = N / 64;  // m-tiles

typedef float fx4 __attribute__((ext_vector_type(4)));
typedef __attribute__((ext_vector_type(8)))  short bf16x8;
typedef __attribute__((ext_vector_type(4)))  short bf16x4;
typedef __attribute__((ext_vector_type(16))) float f32x16;

__device__ inline short f2bf(float x, float* xr) {
  __hip_bfloat16 h = __float2bfloat16(x);
  *xr = __bfloat162float(h);
  short s; __builtin_memcpy(&s, &h, 2);
  return s;
}
__device__ inline short f2bf(float x) {
  __hip_bfloat16 h = __float2bfloat16(x);
  short s; __builtin_memcpy(&s, &h, 2);
  return s;
}

// ---------------- weight-folding GEMMs -> bf16 operands for adjmsg ----------------
// z==0: T slice0 = W1·norm(X) (fp32)   z==1: Tbf = bf16(W2·norm(X))
// z==2: T slice1 = Wres·norm(X) (fp32) z==3: projT = bf16(Ap·X) in (B,N,DK) layout + sqnb
//        (layer 0: projT = bf16(X/sigma) zero-padded to DK rows)
// projT n-major => adjmsg fragment = 8 consecutive shorts = one dwordx4 load.
template<int FIN, bool NORM>
__global__ __launch_bounds__(256) void k_wx(const float* __restrict__ X,     // (B,FIN,N)
                                            const float* __restrict__ sigma, // layer0 only
                                            const float* __restrict__ ssum,  // (2*B*F) ep partials
                                            const float* __restrict__ ssq,
                                            const float* __restrict__ Wc,    // (64,2*FIN)
                                            const float* __restrict__ Wr,    // (64,FIN)
                                            const float* __restrict__ Ap,    // (DK,FIN) or null
                                            float* __restrict__ T,           // (B,2,64,N)
                                            short* __restrict__ Tbf,         // (B,64,N) bf16
                                            short* __restrict__ projT,       // (B,N,DK) bf16
                                            float* __restrict__ sqnb) {      // (B,N)
  int z = blockIdx.z, b = blockIdx.y, n0 = blockIdx.x * 64;
  int t = threadIdx.x, n = t & 63, og = t >> 6;
  __shared__ float xS[64][FIN + 1];
  __shared__ __align__(16) float wT[FIN][68];
  __shared__ float mnS[64], rsS[64];
  __shared__ float sp[4][64];
  for (int e = t; e < FIN * 64; e += 256) {
    int f = e >> 6, nn = e & 63;
    xS[nn][f] = X[((size_t)b * FIN + f) * N + n0 + nn];
  }
  bool l0proj = (z == 3 && Ap == nullptr);
  if (!l0proj) {
    const float* base; int ld, off, OUT;
    if (z == 0)      { base = Wc; ld = 2 * FIN; off = 0;   OUT = 64; }
    else if (z == 1) { base = Wc; ld = 2 * FIN; off = FIN; OUT = 64; }
    else if (z == 2) { base = Wr; ld = FIN;     off = 0;   OUT = 64; }
    else             { base = Ap; ld = FIN;     off = 0;   OUT = DK; }
    for (int e = t; e < OUT * FIN; e += 256) {
      int o = e / FIN, f = e - o * FIN;
      wT[f][o] = base[(size_t)o * ld + off + f];
    }
  }
  if (NORM && z < 3 && t < 64) {  // mean/rstd from ep partial sums (2 halves/row)
    int row = b * FIN + t;
    float S = ssum[2 * row] + ssum[2 * row + 1];
    float Q = ssq[2 * row] + ssq[2 * row + 1];
    float mn = S / (float)N;
    mnS[t] = mn;
    rsS[t] = rsqrtf(Q / (float)N - mn * mn + EPS);
  }
  __syncthreads();
  if (z < 3) {
    float cacc[16] = {};
#pragma unroll 4
    for (int f = 0; f < FIN; ++f) {
      float x = xS[n][f];
      if (NORM) x = (x - mnS[f]) * rsS[f];
      fx4 w0 = *(const fx4*)&wT[f][og * 16 + 0];
      fx4 w1 = *(const fx4*)&wT[f][og * 16 + 4];
      fx4 w2 = *(const fx4*)&wT[f][og * 16 + 8];
      fx4 w3 = *(const fx4*)&wT[f][og * 16 + 12];
#pragma unroll
      for (int k = 0; k < 4; ++k) {
        cacc[k + 0]  = fmaf(w0[k], x, cacc[k + 0]);
        cacc[k + 4]  = fmaf(w1[k], x, cacc[k + 4]);
        cacc[k + 8]  = fmaf(w2[k], x, cacc[k + 8]);
        cacc[k + 12] = fmaf(w3[k], x, cacc[k + 12]);
      }
    }
    if (z == 1) {
#pragma unroll
      for (int k = 0; k < 16; ++k)
        Tbf[((size_t)b * 64 + og * 16 + k) * N + n0 + n] = f2bf(cacc[k]);
    } else {
      int sl = (z == 0) ? 0 : 1;
#pragma unroll
      for (int k = 0; k < 16; ++k)
        T[(((size_t)b * 2 + sl) * 64 + og * 16 + k) * N + n0 + n] = cacc[k];
    }
  } else {
    // proj path: 4 d-rows per thread -> bf16, n-major store (8B), + sqnorm of rounded
    float r[4];
    bf16x4 hv;
    if (Ap != nullptr) {
      float cacc[4] = {};
#pragma unroll 4
      for (int f = 0; f < FIN; ++f) {
        float x = xS[n][f];
        fx4 w0 = *(const fx4*)&wT[f][og * 4];
#pragma unroll
        for (int k = 0; k < 4; ++k) cacc[k] = fmaf(w0[k], x, cacc[k]);
      }
#pragma unroll
      for (int k = 0; k < 4; ++k) hv[k] = f2bf(cacc[k], &r[k]);
    } else {  // layer 0: scaled + zero-padded
      float inv = 1.f / sigma[0];
#pragma unroll
      for (int k = 0; k < 4; ++k) {
        int d = og * 4 + k;
        float v = (d < F0) ? xS[n][d] * inv : 0.f;
        hv[k] = f2bf(v, &r[k]);
      }
    }
    *(bf16x4*)&projT[((size_t)b * N + n0 + n) * DK + og * 4] = hv;
    float s = 0.f;
#pragma unroll
    for (int k = 0; k < 4; ++k) s = fmaf(r[k], r[k], s);
    sp[og][n] = s;
    __syncthreads();
    if (t < 64) sqnb[(size_t)b * N + n0 + t] = sp[0][t] + sp[1][t] + sp[2][t] + sp[3][t];
  }
}

// ---------------- adjacency+deg+PV via bf16 MFMA; n-major proj -> dwordx4 fragments ----------------
__global__ __launch_bounds__(256, 4) void k_adjmsg(const short* __restrict__ projT,  // (B,N,DK)
                                                   const float* __restrict__ sqnb,
                                                   const short* __restrict__ Tbf,
                                                   float* __restrict__ pdmsg,  // (nch,B,F,N)
                                                   float* __restrict__ pdeg,   // (nch,B,N)
                                                   int nch, int cpx) {
  const int NCb = N / nch;
  int i = blockIdx.x;
  int xcd = i & 7;
  int j = i >> 3;
  int lc = j / MT;
  int mtile = j - lc * MT;
  int combo = xcd * cpx + lc;  // bijective XCD swizzle
  int ch = combo >> 2;
  int b  = combo & 3;
  int M0 = mtile * 64;
  int n0 = ch * NCb;

  int t = threadIdx.x;
  int w = t >> 6, l = t & 63;
  int l31 = l & 31, lh = l >> 5;
  int mq = w & 1, nq = w >> 1;
  int fq = w & 1, mq2 = w >> 1;

  const short* pbT = projT + (size_t)b * N * DK;
  const short* vb = Tbf + (size_t)b * F * N;   // bf16 W2·V
  const float* sq = sqnb + (size_t)b * N;

  __shared__ __align__(16) short adjT[2][64][68];
  __shared__ __align__(16) short vS[2][64][68];
  __shared__ float sqmS[64];
  __shared__ float degS[2][64];

  // A-fragment: one dwordx4 per lane (8 consecutive shorts, n-major layout)
  int am = l31 + 32 * mq;
  bf16x8 afrag = *(const bf16x8*)&pbT[(size_t)(M0 + am) * DK + lh * 8];
  if (t < 64) sqmS[t] = sq[M0 + t];
  __syncthreads();
  float sqmr[16];
#pragma unroll
  for (int r = 0; r < 16; ++r)
    sqmr[r] = sqmS[(r & 3) + 8 * (r >> 2) + 4 * lh + 32 * mq];

  f32x16 acc;
#pragma unroll
  for (int r = 0; r < 16; ++r) acc[r] = 0.f;
  float pdm[16];
#pragma unroll
  for (int r = 0; r < 16; ++r) pdm[r] = 0.f;

  int buf = 0;
  for (int nt = 0; nt < NCb; nt += 64) {
    // B-fragment: one dwordx4 per lane + node norm
    int bn = l31 + 32 * nq;
    bf16x8 bfrag = *(const bf16x8*)&pbT[(size_t)(n0 + nt + bn) * DK + lh * 8];
    float sqn_v = sq[n0 + nt + bn];
    {  // stage V: raw bf16 copy, 32B/thread
      int f = t >> 2, nb16 = (t & 3) * 16;
#pragma unroll
      for (int jj = 0; jj < 4; ++jj) {
        *(bf16x4*)&vS[buf][f][nb16 + 4 * jj] =
            *(const bf16x4*)&vb[(size_t)f * N + n0 + nt + nb16 + 4 * jj];
      }
    }
    // gram via MFMA + exp -> adjT[buf]
    f32x16 gz;
#pragma unroll
    for (int r = 0; r < 16; ++r) gz[r] = 0.f;
    f32x16 g = __builtin_amdgcn_mfma_f32_32x32x16_bf16(afrag, bfrag, gz, 0, 0, 0);
#pragma unroll
    for (int r = 0; r < 16; ++r) {
      int m = (r & 3) + 8 * (r >> 2) + 4 * lh + 32 * mq;
      float dist = fmaxf(sqmr[r] + sqn_v - 2.f * g[r], 0.f);
      float a = __expf(-dist);
      pdm[r] += a;
      adjT[buf][m][bn] = f2bf(a);
    }
    __syncthreads();  // adjT[buf]/vS[buf] ready
    // PV via MFMA: acc[f][m] += sum_n V[f][n] * adj[m][n]
#pragma unroll
    for (int kk = 0; kk < 4; ++kk) {
      int nb = kk * 16 + lh * 8;
      int fA = l31 + 32 * fq;
      int mB = l31 + 32 * mq2;
      bf16x4 alo = *(const bf16x4*)&vS[buf][fA][nb];
      bf16x4 ahi = *(const bf16x4*)&vS[buf][fA][nb + 4];
      bf16x4 blo = *(const bf16x4*)&adjT[buf][mB][nb];
      bf16x4 bhi = *(const bf16x4*)&adjT[buf][mB][nb + 4];
      bf16x8 af2, bf2;
#pragma unroll
      for (int i2 = 0; i2 < 4; ++i2) {
        af2[i2] = alo[i2]; af2[i2 + 4] = ahi[i2];
        bf2[i2] = blo[i2]; bf2[i2 + 4] = bhi[i2];
      }
      acc = __builtin_amdgcn_mfma_f32_32x32x16_bf16(af2, bf2, acc, 0, 0, 0);
    }
    buf ^= 1;
  }
#pragma unroll
  for (int r = 0; r < 16; ++r) {
    pdm[r] += __shfl_xor(pdm[r], 1);
    pdm[r] += __shfl_xor(pdm[r], 2);
    pdm[r] += __shfl_xor(pdm[r], 4);
    pdm[r] += __shfl_xor(pdm[r], 8);
    pdm[r] += __shfl_xor(pdm[r], 16);
  }
  if (l31 == 0) {
#pragma unroll
    for (int r = 0; r < 16; ++r)
      degS[nq][(r & 3) + 8 * (r >> 2) + 4 * lh + 32 * mq] = pdm[r];
  }
  __syncthreads();
  if (t < 64) {
    float s = degS[0][t] + degS[1][t];
    __builtin_nontemporal_store(s, &pdeg[(size_t)combo * N + M0 + t]);
  }
  float* pdm_g = pdmsg + (size_t)combo * F * N;
  int m_out = l31 + 32 * mq2;
#pragma unroll
  for (int r = 0; r < 16; ++r) {
    int f_r = (r & 3) + 8 * (r >> 2) + 4 * lh + 32 * fq;
    __builtin_nontemporal_store(acc[r], &pdm_g[(size_t)f_r * N + M0 + m_out]);
  }
}

// ---------------- fused chunk-combine + epilogue + row-stat partials ----------------
template<int CH>
__global__ __launch_bounds__(256) void k_ep(const float* __restrict__ pdmsg,
                                            const float* __restrict__ pdeg,
                                            const float* __restrict__ T,   // (B,2,64,N)
                                            const float* __restrict__ bias,
                                            const float* __restrict__ bres,
                                            float* __restrict__ out,
                                            float* __restrict__ ssum,   // (2*B*F)
                                            float* __restrict__ ssq) {  // (2*B*F)
  int t = threadIdx.x;
  int idx = blockIdx.x * 256 + t;  // fx4 units, total B*F*N/4
  int row = idx >> 9;              // N/4 = 512
  int c4 = idx & 511;
  int o = row & 63, b = row >> 6;
  fx4 dm = {0.f, 0.f, 0.f, 0.f};
  fx4 dg = {0.f, 0.f, 0.f, 0.f};
#pragma unroll
  for (int c = 0; c < CH; ++c) {
    dm += __builtin_nontemporal_load(&((const fx4*)pdmsg)[(((size_t)c * B + b) * 64 + o) * 512 + c4]);
    dg += ((const fx4*)pdeg)[((size_t)c * B + b) * 512 + c4];
  }
  fx4 t0 = ((const fx4*)T)[(((size_t)b * 2 + 0) * 64 + o) * 512 + c4];
  fx4 t2 = ((const fx4*)T)[(((size_t)b * 2 + 1) * 64 + o) * 512 + c4];
  float bi = bias[o], br = bres[o];
  fx4 r = dm + t0 * dg;
  fx4 ov;
#pragma unroll
  for (int j = 0; j < 4; ++j) ov[j] = fmaxf(r[j] + bi, 0.f) + t2[j] + br;
  ((fx4*)out)[((size_t)b * 64 + o) * 512 + c4] = ov;
  float ps = ov[0] + ov[1] + ov[2] + ov[3];
  float pq = fmaf(ov[0], ov[0], fmaf(ov[1], ov[1], fmaf(ov[2], ov[2], ov[3] * ov[3])));
#pragma unroll
  for (int off = 1; off < 64; off <<= 1) {
    ps += __shfl_xor(ps, off);
    pq += __shfl_xor(pq, off);
  }
  __shared__ float r1[4], r2[4];
  if ((t & 63) == 0) { r1[t >> 6] = ps; r2[t >> 6] = pq; }
  __syncthreads();
  if (t == 0) {
    ssum[blockIdx.x] = r1[0] + r1[1] + r1[2] + r1[3];
    ssq[blockIdx.x]  = r2[0] + r2[1] + r2[2] + r2[3];
  }
}

// ---------------- readout from ep partials ----------------
__global__ __launch_bounds__(256) void k_readout(const float* __restrict__ ssum,
                                                 const float* __restrict__ fw,
                                                 const float* __restrict__ fb,
                                                 float* __restrict__ out) {
  int t = threadIdx.x, b = t >> 6, l = t & 63;
  int row = b * 64 + l;
  float po = (ssum[2 * row] + ssum[2 * row + 1]) / (float)N;
  float mn = po;
#pragma unroll
  for (int off = 1; off < 64; off <<= 1) mn += __shfl_xor(mn, off);
  mn *= (1.f / 64.f);
  float d = po - mn;
  float var = d * d;
#pragma unroll
  for (int off = 1; off < 64; off <<= 1) var += __shfl_xor(var, off);
  var *= (1.f / 64.f);
  float rs = rsqrtf(var + EPS);
  float lg = d * rs * fw[l];
#pragma unroll
  for (int off = 1; off < 64; off <<= 1) lg += __shfl_xor(lg, off);
  if (l == 0) out[b] = 1.f / (1.f + __expf(-(lg + fb[0])));
}

}  // namespace

extern "C" void kernel_launch(void* const* d_in, const int* in_sizes, int n_in,
                              void* d_out, int out_size, void* d_ws, size_t ws_size,
                              hipStream_t stream) {
  const float* emb_in   = (const float*)d_in[0];
  const float* sigma    = (const float*)d_in[1];
  const float* fst_w    = (const float*)d_in[2];
  const float* fst_b    = (const float*)d_in[3];
  const float* fst_wres = (const float*)d_in[4];
  const float* fst_bres = (const float*)d_in[5];
  const float* adj_proj = (const float*)d_in[6];
  const float* w        = (const float*)d_in[7];
  const float* bw       = (const float*)d_in[8];
  const float* wres     = (const float*)d_in[9];
  const float* bres     = (const float*)d_in[10];
  const float* fcl_w    = (const float*)d_in[11];
  const float* fcl_b    = (const float*)d_in[12];

  auto need_bytes = [](int nch) -> size_t {
    size_t f = 0;
    f += (size_t)nch * B * N;           // pdeg
    f += (size_t)nch * B * F * N;       // pdmsg
    f += 2 * (size_t)B * F * N;         // embA, embB
    f += 2 * (size_t)B * F * N;         // T (2 slices)
    f += (size_t)B * F * N / 2;         // Tbf (bf16)
    f += (size_t)B * DK * N / 2;        // projT (bf16)
    f += (size_t)B * N;                 // sqnb
    f += 4 * (size_t)B * F;             // ssum, ssq
    return f * 4;
  };
  int nch = (ws_size >= need_bytes(8)) ? 8 : 4;
  int cpx = nch * B / 8;

  float* ws = (float*)d_ws;
  float* pdeg  = ws;  ws += (size_t)nch * B * N;
  float* pdmsg = ws;  ws += (size_t)nch * B * F * N;
  float* embA  = ws;  ws += (size_t)B * F * N;
  float* embB  = ws;  ws += (size_t)B * F * N;
  float* T     = ws;  ws += 2 * (size_t)B * F * N;
  short* Tbf   = (short*)ws;  ws += (size_t)B * F * N / 2;
  short* projT = (short*)ws;  ws += (size_t)B * DK * N / 2;
  float* sqnb  = ws;  ws += (size_t)B * N;
  float* ssum  = ws;  ws += 2 * (size_t)B * F;
  float* ssq   = ws;  ws += 2 * (size_t)B * F;

  constexpr int EPB = (B * F * N / 4) / 256;  // 512 blocks; block = half output row

  // ---- layer 0 ----
  k_wx<F0, false><<<dim3(N / 64, B, 4), 256, 0, stream>>>(
      emb_in, sigma, nullptr, nullptr, fst_w, fst_wres, nullptr, T, Tbf, projT, sqnb);
  k_adjmsg<<<dim3(MT * nch * B), 256, 0, stream>>>(projT, sqnb, Tbf, pdmsg, pdeg, nch, cpx);
  if (nch == 8)
    k_ep<8><<<dim3(EPB), 256, 0, stream>>>(pdmsg, pdeg, T, fst_b, fst_bres, embA, ssum, ssq);
  else
    k_ep<4><<<dim3(EPB), 256, 0, stream>>>(pdmsg, pdeg, T, fst_b, fst_bres, embA, ssum, ssq);

  // ---- layers 1..2 ----
  const float* src = embA;
  float* dst = embB;
  for (int i = 0; i < 2; ++i) {
    k_wx<F, true><<<dim3(N / 64, B, 4), 256, 0, stream>>>(
        src, nullptr, ssum, ssq, w + (size_t)i * F * 2 * F, wres + (size_t)i * F * F,
        adj_proj + (size_t)i * DK * F, T, Tbf, projT, sqnb);
    k_adjmsg<<<dim3(MT * nch * B), 256, 0, stream>>>(projT, sqnb, Tbf, pdmsg, pdeg, nch, cpx);
    if (nch == 8)
      k_ep<8><<<dim3(EPB), 256, 0, stream>>>(pdmsg, pdeg, T, bw + (size_t)i * F,
                                             bres + (size_t)i * F, dst, ssum, ssq);
    else
      k_ep<4><<<dim3(EPB), 256, 0, stream>>>(pdmsg, pdeg, T, bw + (size_t)i * F,
                                             bres + (size_t)i * F, dst, ssum, ssq);
    float* tmp = (float*)src;
    src = dst;
    dst = tmp;
  }

  k_readout<<<dim3(1), 256, 0, stream>>>(ssum, fcl_w, fcl_b, (float*)d_out);
}

// Round 17
// 96.617 us; speedup vs baseline: 4.9580x; 1.0922x over previous
//
#include <hip/hip_runtime.h>
#include <hip/hip_bf16.h>
#include <math.h>

namespace {

constexpr int B  = 4;
constexpr int N  = 2048;
constexpr int F0 = 6;
constexpr int F  = 64;
constexpr int DK = 16;
constexpr float EPS = 1e-5f;
constexpr int MT   = N / 64;  // m-tiles
constexpr int NCH  = 4;       // n-chunks (R17: 8 -> 4, halves partial traffic)

typedef float fx4 __attribute__((ext_vector_type(4)));
typedef __attribute__((ext_vector_type(8)))  short bf16x8;
typedef __attribute__((ext_vector_type(4)))  short bf16x4;
typedef __attribute__((ext_vector_type(16))) float f32x16;

__device__ inline short f2bf(float x, float* xr) {
  __hip_bfloat16 h = __float2bfloat16(x);
  *xr = __bfloat162float(h);
  short s; __builtin_memcpy(&s, &h, 2);
  return s;
}
__device__ inline short f2bf(float x) {
  __hip_bfloat16 h = __float2bfloat16(x);
  short s; __builtin_memcpy(&s, &h, 2);
  return s;
}

// ---------------- weight-folding GEMMs -> bf16 operands for adjmsg ----------------
// z==0: T slice0 = W1·norm(X) (fp32)   z==1: Tbf = bf16(W2·norm(X))
// z==2: T slice1 = Wres·norm(X) (fp32) z==3: projT = bf16(Ap·X) in (B,N,DK) layout + sqnb
//        (layer 0: projT = bf16(X/sigma) zero-padded to DK rows)
template<int FIN, bool NORM>
__global__ __launch_bounds__(256) void k_wx(const float* __restrict__ X,     // (B,FIN,N)
                                            const float* __restrict__ sigma, // layer0 only
                                            const float* __restrict__ ssum,  // (2*B*F) ep partials
                                            const float* __restrict__ ssq,
                                            const float* __restrict__ Wc,    // (64,2*FIN)
                                            const float* __restrict__ Wr,    // (64,FIN)
                                            const float* __restrict__ Ap,    // (DK,FIN) or null
                                            float* __restrict__ T,           // (B,2,64,N)
                                            short* __restrict__ Tbf,         // (B,64,N) bf16
                                            short* __restrict__ projT,       // (B,N,DK) bf16
                                            float* __restrict__ sqnb) {      // (B,N)
  int z = blockIdx.z, b = blockIdx.y, n0 = blockIdx.x * 64;
  int t = threadIdx.x, n = t & 63, og = t >> 6;
  __shared__ float xS[64][FIN + 1];
  __shared__ __align__(16) float wT[FIN][68];
  __shared__ float mnS[64], rsS[64];
  __shared__ float sp[4][64];
  for (int e = t; e < FIN * 64; e += 256) {
    int f = e >> 6, nn = e & 63;
    xS[nn][f] = X[((size_t)b * FIN + f) * N + n0 + nn];
  }
  bool l0proj = (z == 3 && Ap == nullptr);
  if (!l0proj) {
    const float* base; int ld, off, OUT;
    if (z == 0)      { base = Wc; ld = 2 * FIN; off = 0;   OUT = 64; }
    else if (z == 1) { base = Wc; ld = 2 * FIN; off = FIN; OUT = 64; }
    else if (z == 2) { base = Wr; ld = FIN;     off = 0;   OUT = 64; }
    else             { base = Ap; ld = FIN;     off = 0;   OUT = DK; }
    for (int e = t; e < OUT * FIN; e += 256) {
      int o = e / FIN, f = e - o * FIN;
      wT[f][o] = base[(size_t)o * ld + off + f];
    }
  }
  if (NORM && z < 3 && t < 64) {  // mean/rstd from ep partial sums (2 halves/row)
    int row = b * FIN + t;
    float S = ssum[2 * row] + ssum[2 * row + 1];
    float Q = ssq[2 * row] + ssq[2 * row + 1];
    float mn = S / (float)N;
    mnS[t] = mn;
    rsS[t] = rsqrtf(Q / (float)N - mn * mn + EPS);
  }
  __syncthreads();
  if (z < 3) {
    float cacc[16] = {};
#pragma unroll 4
    for (int f = 0; f < FIN; ++f) {
      float x = xS[n][f];
      if (NORM) x = (x - mnS[f]) * rsS[f];
      fx4 w0 = *(const fx4*)&wT[f][og * 16 + 0];
      fx4 w1 = *(const fx4*)&wT[f][og * 16 + 4];
      fx4 w2 = *(const fx4*)&wT[f][og * 16 + 8];
      fx4 w3 = *(const fx4*)&wT[f][og * 16 + 12];
#pragma unroll
      for (int k = 0; k < 4; ++k) {
        cacc[k + 0]  = fmaf(w0[k], x, cacc[k + 0]);
        cacc[k + 4]  = fmaf(w1[k], x, cacc[k + 4]);
        cacc[k + 8]  = fmaf(w2[k], x, cacc[k + 8]);
        cacc[k + 12] = fmaf(w3[k], x, cacc[k + 12]);
      }
    }
    if (z == 1) {
#pragma unroll
      for (int k = 0; k < 16; ++k)
        Tbf[((size_t)b * 64 + og * 16 + k) * N + n0 + n] = f2bf(cacc[k]);
    } else {
      int sl = (z == 0) ? 0 : 1;
#pragma unroll
      for (int k = 0; k < 16; ++k)
        T[(((size_t)b * 2 + sl) * 64 + og * 16 + k) * N + n0 + n] = cacc[k];
    }
  } else {
    // proj path: 4 d-rows per thread -> bf16, n-major store (8B), + sqnorm of rounded
    float r[4];
    bf16x4 hv;
    if (Ap != nullptr) {
      float cacc[4] = {};
#pragma unroll 4
      for (int f = 0; f < FIN; ++f) {
        float x = xS[n][f];
        fx4 w0 = *(const fx4*)&wT[f][og * 4];
#pragma unroll
        for (int k = 0; k < 4; ++k) cacc[k] = fmaf(w0[k], x, cacc[k]);
      }
#pragma unroll
      for (int k = 0; k < 4; ++k) hv[k] = f2bf(cacc[k], &r[k]);
    } else {  // layer 0: scaled + zero-padded
      float inv = 1.f / sigma[0];
#pragma unroll
      for (int k = 0; k < 4; ++k) {
        int d = og * 4 + k;
        float v = (d < F0) ? xS[n][d] * inv : 0.f;
        hv[k] = f2bf(v, &r[k]);
      }
    }
    *(bf16x4*)&projT[((size_t)b * N + n0 + n) * DK + og * 4] = hv;
    float s = 0.f;
#pragma unroll
    for (int k = 0; k < 4; ++k) s = fmaf(r[k], r[k], s);
    sp[og][n] = s;
    __syncthreads();
    if (t < 64) sqnb[(size_t)b * N + n0 + t] = sp[0][t] + sp[1][t] + sp[2][t] + sp[3][t];
  }
}

// ---------------- adjacency+deg+PV via bf16 MFMA; n-major proj -> dwordx4 fragments ----------------
__global__ __launch_bounds__(256, 4) void k_adjmsg(const short* __restrict__ projT,  // (B,N,DK)
                                                   const float* __restrict__ sqnb,
                                                   const short* __restrict__ Tbf,
                                                   float* __restrict__ pdmsg,  // (NCH,B,F,N)
                                                   float* __restrict__ pdeg) { // (NCH,B,N)
  constexpr int NCb = N / NCH;      // 512
  constexpr int CPX = NCH * B / 8;  // 2 combos per XCD
  int i = blockIdx.x;
  int xcd = i & 7;
  int j = i >> 3;
  int lc = j / MT;
  int mtile = j - lc * MT;
  int combo = xcd * CPX + lc;  // bijective XCD swizzle
  int ch = combo >> 2;
  int b  = combo & 3;
  int M0 = mtile * 64;
  int n0 = ch * NCb;

  int t = threadIdx.x;
  int w = t >> 6, l = t & 63;
  int l31 = l & 31, lh = l >> 5;
  int mq = w & 1, nq = w >> 1;
  int fq = w & 1, mq2 = w >> 1;

  const short* pbT = projT + (size_t)b * N * DK;
  const short* vb = Tbf + (size_t)b * F * N;   // bf16 W2·V
  const float* sq = sqnb + (size_t)b * N;

  __shared__ __align__(16) short adjT[2][64][68];
  __shared__ __align__(16) short vS[2][64][68];
  __shared__ float sqmS[64];
  __shared__ float degS[2][64];

  // A-fragment: one dwordx4 per lane (8 consecutive shorts, n-major layout)
  int am = l31 + 32 * mq;
  bf16x8 afrag = *(const bf16x8*)&pbT[(size_t)(M0 + am) * DK + lh * 8];
  if (t < 64) sqmS[t] = sq[M0 + t];
  __syncthreads();
  float sqmr[16];
#pragma unroll
  for (int r = 0; r < 16; ++r)
    sqmr[r] = sqmS[(r & 3) + 8 * (r >> 2) + 4 * lh + 32 * mq];

  f32x16 acc;
#pragma unroll
  for (int r = 0; r < 16; ++r) acc[r] = 0.f;
  float pdm[16];
#pragma unroll
  for (int r = 0; r < 16; ++r) pdm[r] = 0.f;

  int buf = 0;
  for (int nt = 0; nt < NCb; nt += 64) {
    // B-fragment: one dwordx4 per lane + node norm
    int bn = l31 + 32 * nq;
    bf16x8 bfrag = *(const bf16x8*)&pbT[(size_t)(n0 + nt + bn) * DK + lh * 8];
    float sqn_v = sq[n0 + nt + bn];
    {  // stage V: raw bf16 copy, 32B/thread
      int f = t >> 2, nb16 = (t & 3) * 16;
#pragma unroll
      for (int jj = 0; jj < 4; ++jj) {
        *(bf16x4*)&vS[buf][f][nb16 + 4 * jj] =
            *(const bf16x4*)&vb[(size_t)f * N + n0 + nt + nb16 + 4 * jj];
      }
    }
    // gram via MFMA + exp -> adjT[buf]
    f32x16 gz;
#pragma unroll
    for (int r = 0; r < 16; ++r) gz[r] = 0.f;
    f32x16 g = __builtin_amdgcn_mfma_f32_32x32x16_bf16(afrag, bfrag, gz, 0, 0, 0);
#pragma unroll
    for (int r = 0; r < 16; ++r) {
      int m = (r & 3) + 8 * (r >> 2) + 4 * lh + 32 * mq;
      float dist = fmaxf(sqmr[r] + sqn_v - 2.f * g[r], 0.f);
      float a = __expf(-dist);
      pdm[r] += a;
      adjT[buf][m][bn] = f2bf(a);
    }
    __syncthreads();  // adjT[buf]/vS[buf] ready
    // PV via MFMA: acc[f][m] += sum_n V[f][n] * adj[m][n]
#pragma unroll
    for (int kk = 0; kk < 4; ++kk) {
      int nb = kk * 16 + lh * 8;
      int fA = l31 + 32 * fq;
      int mB = l31 + 32 * mq2;
      bf16x4 alo = *(const bf16x4*)&vS[buf][fA][nb];
      bf16x4 ahi = *(const bf16x4*)&vS[buf][fA][nb + 4];
      bf16x4 blo = *(const bf16x4*)&adjT[buf][mB][nb];
      bf16x4 bhi = *(const bf16x4*)&adjT[buf][mB][nb + 4];
      bf16x8 af2, bf2;
#pragma unroll
      for (int i2 = 0; i2 < 4; ++i2) {
        af2[i2] = alo[i2]; af2[i2 + 4] = ahi[i2];
        bf2[i2] = blo[i2]; bf2[i2 + 4] = bhi[i2];
      }
      acc = __builtin_amdgcn_mfma_f32_32x32x16_bf16(af2, bf2, acc, 0, 0, 0);
    }
    buf ^= 1;
  }
#pragma unroll
  for (int r = 0; r < 16; ++r) {
    pdm[r] += __shfl_xor(pdm[r], 1);
    pdm[r] += __shfl_xor(pdm[r], 2);
    pdm[r] += __shfl_xor(pdm[r], 4);
    pdm[r] += __shfl_xor(pdm[r], 8);
    pdm[r] += __shfl_xor(pdm[r], 16);
  }
  if (l31 == 0) {
#pragma unroll
    for (int r = 0; r < 16; ++r)
      degS[nq][(r & 3) + 8 * (r >> 2) + 4 * lh + 32 * mq] = pdm[r];
  }
  __syncthreads();
  if (t < 64) {
    float s = degS[0][t] + degS[1][t];
    __builtin_nontemporal_store(s, &pdeg[(size_t)combo * N + M0 + t]);
  }
  float* pdm_g = pdmsg + (size_t)combo * F * N;
  int m_out = l31 + 32 * mq2;
#pragma unroll
  for (int r = 0; r < 16; ++r) {
    int f_r = (r & 3) + 8 * (r >> 2) + 4 * lh + 32 * fq;
    __builtin_nontemporal_store(acc[r], &pdm_g[(size_t)f_r * N + M0 + m_out]);
  }
}

// ---------------- fused chunk-combine + epilogue + row-stat partials ----------------
__global__ __launch_bounds__(256) void k_ep(const float* __restrict__ pdmsg,
                                            const float* __restrict__ pdeg,
                                            const float* __restrict__ T,   // (B,2,64,N)
                                            const float* __restrict__ bias,
                                            const float* __restrict__ bres,
                                            float* __restrict__ out,
                                            float* __restrict__ ssum,   // (2*B*F)
                                            float* __restrict__ ssq) {  // (2*B*F)
  int t = threadIdx.x;
  int idx = blockIdx.x * 256 + t;  // fx4 units, total B*F*N/4
  int row = idx >> 9;              // N/4 = 512
  int c4 = idx & 511;
  int o = row & 63, b = row >> 6;
  fx4 dm = {0.f, 0.f, 0.f, 0.f};
  fx4 dg = {0.f, 0.f, 0.f, 0.f};
#pragma unroll
  for (int c = 0; c < NCH; ++c) {
    dm += __builtin_nontemporal_load(&((const fx4*)pdmsg)[(((size_t)c * B + b) * 64 + o) * 512 + c4]);
    dg += ((const fx4*)pdeg)[((size_t)c * B + b) * 512 + c4];
  }
  fx4 t0 = ((const fx4*)T)[(((size_t)b * 2 + 0) * 64 + o) * 512 + c4];
  fx4 t2 = ((const fx4*)T)[(((size_t)b * 2 + 1) * 64 + o) * 512 + c4];
  float bi = bias[o], br = bres[o];
  fx4 r = dm + t0 * dg;
  fx4 ov;
#pragma unroll
  for (int j = 0; j < 4; ++j) ov[j] = fmaxf(r[j] + bi, 0.f) + t2[j] + br;
  ((fx4*)out)[((size_t)b * 64 + o) * 512 + c4] = ov;
  float ps = ov[0] + ov[1] + ov[2] + ov[3];
  float pq = fmaf(ov[0], ov[0], fmaf(ov[1], ov[1], fmaf(ov[2], ov[2], ov[3] * ov[3])));
#pragma unroll
  for (int off = 1; off < 64; off <<= 1) {
    ps += __shfl_xor(ps, off);
    pq += __shfl_xor(pq, off);
  }
  __shared__ float r1[4], r2[4];
  if ((t & 63) == 0) { r1[t >> 6] = ps; r2[t >> 6] = pq; }
  __syncthreads();
  if (t == 0) {
    ssum[blockIdx.x] = r1[0] + r1[1] + r1[2] + r1[3];
    ssq[blockIdx.x]  = r2[0] + r2[1] + r2[2] + r2[3];
  }
}

// ---------------- readout from ep partials ----------------
__global__ __launch_bounds__(256) void k_readout(const float* __restrict__ ssum,
                                                 const float* __restrict__ fw,
                                                 const float* __restrict__ fb,
                                                 float* __restrict__ out) {
  int t = threadIdx.x, b = t >> 6, l = t & 63;
  int row = b * 64 + l;
  float po = (ssum[2 * row] + ssum[2 * row + 1]) / (float)N;
  float mn = po;
#pragma unroll
  for (int off = 1; off < 64; off <<= 1) mn += __shfl_xor(mn, off);
  mn *= (1.f / 64.f);
  float d = po - mn;
  float var = d * d;
#pragma unroll
  for (int off = 1; off < 64; off <<= 1) var += __shfl_xor(var, off);
  var *= (1.f / 64.f);
  float rs = rsqrtf(var + EPS);
  float lg = d * rs * fw[l];
#pragma unroll
  for (int off = 1; off < 64; off <<= 1) lg += __shfl_xor(lg, off);
  if (l == 0) out[b] = 1.f / (1.f + __expf(-(lg + fb[0])));
}

}  // namespace

extern "C" void kernel_launch(void* const* d_in, const int* in_sizes, int n_in,
                              void* d_out, int out_size, void* d_ws, size_t ws_size,
                              hipStream_t stream) {
  const float* emb_in   = (const float*)d_in[0];
  const float* sigma    = (const float*)d_in[1];
  const float* fst_w    = (const float*)d_in[2];
  const float* fst_b    = (const float*)d_in[3];
  const float* fst_wres = (const float*)d_in[4];
  const float* fst_bres = (const float*)d_in[5];
  const float* adj_proj = (const float*)d_in[6];
  const float* w        = (const float*)d_in[7];
  const float* bw       = (const float*)d_in[8];
  const float* wres     = (const float*)d_in[9];
  const float* bres     = (const float*)d_in[10];
  const float* fcl_w    = (const float*)d_in[11];
  const float* fcl_b    = (const float*)d_in[12];

  float* ws = (float*)d_ws;
  float* pdeg  = ws;  ws += (size_t)NCH * B * N;
  float* pdmsg = ws;  ws += (size_t)NCH * B * F * N;
  float* embA  = ws;  ws += (size_t)B * F * N;
  float* embB  = ws;  ws += (size_t)B * F * N;
  float* T     = ws;  ws += 2 * (size_t)B * F * N;
  short* Tbf   = (short*)ws;  ws += (size_t)B * F * N / 2;
  short* projT = (short*)ws;  ws += (size_t)B * DK * N / 2;
  float* sqnb  = ws;  ws += (size_t)B * N;
  float* ssum  = ws;  ws += 2 * (size_t)B * F;
  float* ssq   = ws;  ws += 2 * (size_t)B * F;

  constexpr int EPB = (B * F * N / 4) / 256;  // 512 blocks; block = half output row
  constexpr int AJB = MT * NCH * B;           // 512 blocks

  // ---- layer 0 ----
  k_wx<F0, false><<<dim3(N / 64, B, 4), 256, 0, stream>>>(
      emb_in, sigma, nullptr, nullptr, fst_w, fst_wres, nullptr, T, Tbf, projT, sqnb);
  k_adjmsg<<<dim3(AJB), 256, 0, stream>>>(projT, sqnb, Tbf, pdmsg, pdeg);
  k_ep<<<dim3(EPB), 256, 0, stream>>>(pdmsg, pdeg, T, fst_b, fst_bres, embA, ssum, ssq);

  // ---- layers 1..2 ----
  const float* src = embA;
  float* dst = embB;
  for (int i = 0; i < 2; ++i) {
    k_wx<F, true><<<dim3(N / 64, B, 4), 256, 0, stream>>>(
        src, nullptr, ssum, ssq, w + (size_t)i * F * 2 * F, wres + (size_t)i * F * F,
        adj_proj + (size_t)i * DK * F, T, Tbf, projT, sqnb);
    k_adjmsg<<<dim3(AJB), 256, 0, stream>>>(projT, sqnb, Tbf, pdmsg, pdeg);
    k_ep<<<dim3(EPB), 256, 0, stream>>>(pdmsg, pdeg, T, bw + (size_t)i * F,
                                        bres + (size_t)i * F, dst, ssum, ssq);
    float* tmp = (float*)src;
    src = dst;
    dst = tmp;
  }

  k_readout<<<dim3(1), 256, 0, stream>>>(ssum, fcl_w, fcl_b, (float*)d_out);
}

// Round 18
// 88.670 us; speedup vs baseline: 5.4024x; 1.0896x over previous
//
#include <hip/hip_runtime.h>
#include <hip/hip_bf16.h>
#include <math.h>

namespace {

constexpr int B  = 4;
constexpr int N  = 2048;
constexpr int F0 = 6;
constexpr int F  = 64;
constexpr int DK = 16;
constexpr float EPS = 1e-5f;
constexpr int MT   = N / 64;  // m-tiles
constexpr int NCH  = 4;       // n-chunks

typedef float fx4 __attribute__((ext_vector_type(4)));
typedef __attribute__((ext_vector_type(8)))  short bf16x8;
typedef __attribute__((ext_vector_type(4)))  short bf16x4;
typedef __attribute__((ext_vector_type(16))) float f32x16;

__device__ inline short f2bf(float x, float* xr) {
  __hip_bfloat16 h = __float2bfloat16(x);
  *xr = __bfloat162float(h);
  short s; __builtin_memcpy(&s, &h, 2);
  return s;
}
__device__ inline short f2bf(float x) {
  __hip_bfloat16 h = __float2bfloat16(x);
  short s; __builtin_memcpy(&s, &h, 2);
  return s;
}
__device__ inline float bf2f(short s) {
  unsigned int u = ((unsigned int)(unsigned short)s) << 16;
  float f; __builtin_memcpy(&f, &u, 4);
  return f;
}

// ---------------- weight-folding GEMMs -> bf16 operands for adjmsg ----------------
// z==0: T slice0 = W1·norm(X) (fp32)   z==1: Tbf = bf16(W2·norm(X))
// z==2: T slice1 = Wres·norm(X) (fp32) z==3: projT = bf16(Ap·X) in (B,N,DK) layout + sqnb
//        (layer 0: projT = bf16(X/sigma) zero-padded to DK rows)
template<int FIN, bool NORM>
__global__ __launch_bounds__(256) void k_wx(const float* __restrict__ X,     // (B,FIN,N)
                                            const float* __restrict__ sigma, // layer0 only
                                            const float* __restrict__ ssum,  // (2*B*F) ep partials
                                            const float* __restrict__ ssq,
                                            const float* __restrict__ Wc,    // (64,2*FIN)
                                            const float* __restrict__ Wr,    // (64,FIN)
                                            const float* __restrict__ Ap,    // (DK,FIN) or null
                                            float* __restrict__ T,           // (B,2,64,N)
                                            short* __restrict__ Tbf,         // (B,64,N) bf16
                                            short* __restrict__ projT,       // (B,N,DK) bf16
                                            float* __restrict__ sqnb) {      // (B,N)
  int z = blockIdx.z, b = blockIdx.y, n0 = blockIdx.x * 64;
  int t = threadIdx.x, n = t & 63, og = t >> 6;
  __shared__ float xS[64][FIN + 1];
  __shared__ __align__(16) float wT[FIN][68];
  __shared__ float mnS[64], rsS[64];
  __shared__ float sp[4][64];
  for (int e = t; e < FIN * 64; e += 256) {
    int f = e >> 6, nn = e & 63;
    xS[nn][f] = X[((size_t)b * FIN + f) * N + n0 + nn];
  }
  bool l0proj = (z == 3 && Ap == nullptr);
  if (!l0proj) {
    const float* base; int ld, off, OUT;
    if (z == 0)      { base = Wc; ld = 2 * FIN; off = 0;   OUT = 64; }
    else if (z == 1) { base = Wc; ld = 2 * FIN; off = FIN; OUT = 64; }
    else if (z == 2) { base = Wr; ld = FIN;     off = 0;   OUT = 64; }
    else             { base = Ap; ld = FIN;     off = 0;   OUT = DK; }
    for (int e = t; e < OUT * FIN; e += 256) {
      int o = e / FIN, f = e - o * FIN;
      wT[f][o] = base[(size_t)o * ld + off + f];
    }
  }
  if (NORM && z < 3 && t < 64) {  // mean/rstd from ep partial sums (2 halves/row)
    int row = b * FIN + t;
    float S = ssum[2 * row] + ssum[2 * row + 1];
    float Q = ssq[2 * row] + ssq[2 * row + 1];
    float mn = S / (float)N;
    mnS[t] = mn;
    rsS[t] = rsqrtf(Q / (float)N - mn * mn + EPS);
  }
  __syncthreads();
  if (z < 3) {
    float cacc[16] = {};
#pragma unroll 4
    for (int f = 0; f < FIN; ++f) {
      float x = xS[n][f];
      if (NORM) x = (x - mnS[f]) * rsS[f];
      fx4 w0 = *(const fx4*)&wT[f][og * 16 + 0];
      fx4 w1 = *(const fx4*)&wT[f][og * 16 + 4];
      fx4 w2 = *(const fx4*)&wT[f][og * 16 + 8];
      fx4 w3 = *(const fx4*)&wT[f][og * 16 + 12];
#pragma unroll
      for (int k = 0; k < 4; ++k) {
        cacc[k + 0]  = fmaf(w0[k], x, cacc[k + 0]);
        cacc[k + 4]  = fmaf(w1[k], x, cacc[k + 4]);
        cacc[k + 8]  = fmaf(w2[k], x, cacc[k + 8]);
        cacc[k + 12] = fmaf(w3[k], x, cacc[k + 12]);
      }
    }
    if (z == 1) {
#pragma unroll
      for (int k = 0; k < 16; ++k)
        Tbf[((size_t)b * 64 + og * 16 + k) * N + n0 + n] = f2bf(cacc[k]);
    } else {
      int sl = (z == 0) ? 0 : 1;
#pragma unroll
      for (int k = 0; k < 16; ++k)
        T[(((size_t)b * 2 + sl) * 64 + og * 16 + k) * N + n0 + n] = cacc[k];
    }
  } else {
    // proj path: 4 d-rows per thread -> bf16, n-major store (8B), + sqnorm of rounded
    float r[4];
    bf16x4 hv;
    if (Ap != nullptr) {
      float cacc[4] = {};
#pragma unroll 4
      for (int f = 0; f < FIN; ++f) {
        float x = xS[n][f];
        fx4 w0 = *(const fx4*)&wT[f][og * 4];
#pragma unroll
        for (int k = 0; k < 4; ++k) cacc[k] = fmaf(w0[k], x, cacc[k]);
      }
#pragma unroll
      for (int k = 0; k < 4; ++k) hv[k] = f2bf(cacc[k], &r[k]);
    } else {  // layer 0: scaled + zero-padded
      float inv = 1.f / sigma[0];
#pragma unroll
      for (int k = 0; k < 4; ++k) {
        int d = og * 4 + k;
        float v = (d < F0) ? xS[n][d] * inv : 0.f;
        hv[k] = f2bf(v, &r[k]);
      }
    }
    *(bf16x4*)&projT[((size_t)b * N + n0 + n) * DK + og * 4] = hv;
    float s = 0.f;
#pragma unroll
    for (int k = 0; k < 4; ++k) s = fmaf(r[k], r[k], s);
    sp[og][n] = s;
    __syncthreads();
    if (t < 64) sqnb[(size_t)b * N + n0 + t] = sp[0][t] + sp[1][t] + sp[2][t] + sp[3][t];
  }
}

// ---------------- adjacency+deg+PV via bf16 MFMA; bf16 partial outputs ----------------
__global__ __launch_bounds__(256, 4) void k_adjmsg(const short* __restrict__ projT,  // (B,N,DK)
                                                   const float* __restrict__ sqnb,
                                                   const short* __restrict__ Tbf,
                                                   short* __restrict__ pdmsg,  // (NCH,B,F,N) bf16
                                                   float* __restrict__ pdeg) { // (NCH,B,N)
  constexpr int NCb = N / NCH;      // 512
  constexpr int CPX = NCH * B / 8;  // 2 combos per XCD
  int i = blockIdx.x;
  int xcd = i & 7;
  int j = i >> 3;
  int lc = j / MT;
  int mtile = j - lc * MT;
  int combo = xcd * CPX + lc;  // bijective XCD swizzle
  int ch = combo >> 2;
  int b  = combo & 3;
  int M0 = mtile * 64;
  int n0 = ch * NCb;

  int t = threadIdx.x;
  int w = t >> 6, l = t & 63;
  int l31 = l & 31, lh = l >> 5;
  int mq = w & 1, nq = w >> 1;
  int fq = w & 1, mq2 = w >> 1;

  const short* pbT = projT + (size_t)b * N * DK;
  const short* vb = Tbf + (size_t)b * F * N;   // bf16 W2·V
  const float* sq = sqnb + (size_t)b * N;

  __shared__ __align__(16) short adjT[2][64][68];
  __shared__ __align__(16) short vS[2][64][68];
  __shared__ float sqmS[64];
  __shared__ float degS[2][64];

  // A-fragment: one dwordx4 per lane (8 consecutive shorts, n-major layout)
  int am = l31 + 32 * mq;
  bf16x8 afrag = *(const bf16x8*)&pbT[(size_t)(M0 + am) * DK + lh * 8];
  if (t < 64) sqmS[t] = sq[M0 + t];
  __syncthreads();
  float sqmr[16];
#pragma unroll
  for (int r = 0; r < 16; ++r)
    sqmr[r] = sqmS[(r & 3) + 8 * (r >> 2) + 4 * lh + 32 * mq];

  f32x16 acc;
#pragma unroll
  for (int r = 0; r < 16; ++r) acc[r] = 0.f;
  float pdm[16];
#pragma unroll
  for (int r = 0; r < 16; ++r) pdm[r] = 0.f;

  int buf = 0;
  for (int nt = 0; nt < NCb; nt += 64) {
    // B-fragment: one dwordx4 per lane + node norm
    int bn = l31 + 32 * nq;
    bf16x8 bfrag = *(const bf16x8*)&pbT[(size_t)(n0 + nt + bn) * DK + lh * 8];
    float sqn_v = sq[n0 + nt + bn];
    {  // stage V: raw bf16 copy, 32B/thread
      int f = t >> 2, nb16 = (t & 3) * 16;
#pragma unroll
      for (int jj = 0; jj < 4; ++jj) {
        *(bf16x4*)&vS[buf][f][nb16 + 4 * jj] =
            *(const bf16x4*)&vb[(size_t)f * N + n0 + nt + nb16 + 4 * jj];
      }
    }
    // gram via MFMA + exp -> adjT[buf]
    f32x16 gz;
#pragma unroll
    for (int r = 0; r < 16; ++r) gz[r] = 0.f;
    f32x16 g = __builtin_amdgcn_mfma_f32_32x32x16_bf16(afrag, bfrag, gz, 0, 0, 0);
#pragma unroll
    for (int r = 0; r < 16; ++r) {
      int m = (r & 3) + 8 * (r >> 2) + 4 * lh + 32 * mq;
      float dist = fmaxf(sqmr[r] + sqn_v - 2.f * g[r], 0.f);
      float a = __expf(-dist);
      pdm[r] += a;
      adjT[buf][m][bn] = f2bf(a);
    }
    __syncthreads();  // adjT[buf]/vS[buf] ready
    // PV via MFMA: acc[f][m] += sum_n V[f][n] * adj[m][n]
#pragma unroll
    for (int kk = 0; kk < 4; ++kk) {
      int nb = kk * 16 + lh * 8;
      int fA = l31 + 32 * fq;
      int mB = l31 + 32 * mq2;
      bf16x4 alo = *(const bf16x4*)&vS[buf][fA][nb];
      bf16x4 ahi = *(const bf16x4*)&vS[buf][fA][nb + 4];
      bf16x4 blo = *(const bf16x4*)&adjT[buf][mB][nb];
      bf16x4 bhi = *(const bf16x4*)&adjT[buf][mB][nb + 4];
      bf16x8 af2, bf2;
#pragma unroll
      for (int i2 = 0; i2 < 4; ++i2) {
        af2[i2] = alo[i2]; af2[i2 + 4] = ahi[i2];
        bf2[i2] = blo[i2]; bf2[i2 + 4] = bhi[i2];
      }
      acc = __builtin_amdgcn_mfma_f32_32x32x16_bf16(af2, bf2, acc, 0, 0, 0);
    }
    buf ^= 1;
  }
#pragma unroll
  for (int r = 0; r < 16; ++r) {
    pdm[r] += __shfl_xor(pdm[r], 1);
    pdm[r] += __shfl_xor(pdm[r], 2);
    pdm[r] += __shfl_xor(pdm[r], 4);
    pdm[r] += __shfl_xor(pdm[r], 8);
    pdm[r] += __shfl_xor(pdm[r], 16);
  }
  if (l31 == 0) {
#pragma unroll
    for (int r = 0; r < 16; ++r)
      degS[nq][(r & 3) + 8 * (r >> 2) + 4 * lh + 32 * mq] = pdm[r];
  }
  __syncthreads();
  if (t < 64) {
    float s = degS[0][t] + degS[1][t];
    __builtin_nontemporal_store(s, &pdeg[(size_t)combo * N + M0 + t]);
  }
  short* pdm_g = pdmsg + (size_t)combo * F * N;
  int m_out = l31 + 32 * mq2;
#pragma unroll
  for (int r = 0; r < 16; ++r) {
    int f_r = (r & 3) + 8 * (r >> 2) + 4 * lh + 32 * fq;
    __builtin_nontemporal_store(f2bf(acc[r]), &pdm_g[(size_t)f_r * N + M0 + m_out]);
  }
}

// ---------------- fused chunk-combine + epilogue + row-stat partials ----------------
__global__ __launch_bounds__(256) void k_ep(const short* __restrict__ pdmsg,  // bf16
                                            const float* __restrict__ pdeg,
                                            const float* __restrict__ T,   // (B,2,64,N)
                                            const float* __restrict__ bias,
                                            const float* __restrict__ bres,
                                            float* __restrict__ out,
                                            float* __restrict__ ssum,   // (2*B*F)
                                            float* __restrict__ ssq) {  // (2*B*F)
  int t = threadIdx.x;
  int idx = blockIdx.x * 256 + t;  // fx4 units, total B*F*N/4
  int row = idx >> 9;              // N/4 = 512
  int c4 = idx & 511;
  int o = row & 63, b = row >> 6;
  fx4 dm = {0.f, 0.f, 0.f, 0.f};
  fx4 dg = {0.f, 0.f, 0.f, 0.f};
#pragma unroll
  for (int c = 0; c < NCH; ++c) {
    bf16x4 pv = __builtin_nontemporal_load(
        &((const bf16x4*)pdmsg)[(((size_t)c * B + b) * 64 + o) * 512 + c4]);
#pragma unroll
    for (int j = 0; j < 4; ++j) dm[j] += bf2f(pv[j]);
    dg += ((const fx4*)pdeg)[((size_t)c * B + b) * 512 + c4];
  }
  fx4 t0 = ((const fx4*)T)[(((size_t)b * 2 + 0) * 64 + o) * 512 + c4];
  fx4 t2 = ((const fx4*)T)[(((size_t)b * 2 + 1) * 64 + o) * 512 + c4];
  float bi = bias[o], br = bres[o];
  fx4 r = dm + t0 * dg;
  fx4 ov;
#pragma unroll
  for (int j = 0; j < 4; ++j) ov[j] = fmaxf(r[j] + bi, 0.f) + t2[j] + br;
  ((fx4*)out)[((size_t)b * 64 + o) * 512 + c4] = ov;
  float ps = ov[0] + ov[1] + ov[2] + ov[3];
  float pq = fmaf(ov[0], ov[0], fmaf(ov[1], ov[1], fmaf(ov[2], ov[2], ov[3] * ov[3])));
#pragma unroll
  for (int off = 1; off < 64; off <<= 1) {
    ps += __shfl_xor(ps, off);
    pq += __shfl_xor(pq, off);
  }
  __shared__ float r1[4], r2[4];
  if ((t & 63) == 0) { r1[t >> 6] = ps; r2[t >> 6] = pq; }
  __syncthreads();
  if (t == 0) {
    ssum[blockIdx.x] = r1[0] + r1[1] + r1[2] + r1[3];
    ssq[blockIdx.x]  = r2[0] + r2[1] + r2[2] + r2[3];
  }
}

// ---------------- readout from ep partials ----------------
__global__ __launch_bounds__(256) void k_readout(const float* __restrict__ ssum,
                                                 const float* __restrict__ fw,
                                                 const float* __restrict__ fb,
                                                 float* __restrict__ out) {
  int t = threadIdx.x, b = t >> 6, l = t & 63;
  int row = b * 64 + l;
  float po = (ssum[2 * row] + ssum[2 * row + 1]) / (float)N;
  float mn = po;
#pragma unroll
  for (int off = 1; off < 64; off <<= 1) mn += __shfl_xor(mn, off);
  mn *= (1.f / 64.f);
  float d = po - mn;
  float var = d * d;
#pragma unroll
  for (int off = 1; off < 64; off <<= 1) var += __shfl_xor(var, off);
  var *= (1.f / 64.f);
  float rs = rsqrtf(var + EPS);
  float lg = d * rs * fw[l];
#pragma unroll
  for (int off = 1; off < 64; off <<= 1) lg += __shfl_xor(lg, off);
  if (l == 0) out[b] = 1.f / (1.f + __expf(-(lg + fb[0])));
}

}  // namespace

extern "C" void kernel_launch(void* const* d_in, const int* in_sizes, int n_in,
                              void* d_out, int out_size, void* d_ws, size_t ws_size,
                              hipStream_t stream) {
  const float* emb_in   = (const float*)d_in[0];
  const float* sigma    = (const float*)d_in[1];
  const float* fst_w    = (const float*)d_in[2];
  const float* fst_b    = (const float*)d_in[3];
  const float* fst_wres = (const float*)d_in[4];
  const float* fst_bres = (const float*)d_in[5];
  const float* adj_proj = (const float*)d_in[6];
  const float* w        = (const float*)d_in[7];
  const float* bw       = (const float*)d_in[8];
  const float* wres     = (const float*)d_in[9];
  const float* bres     = (const float*)d_in[10];
  const float* fcl_w    = (const float*)d_in[11];
  const float* fcl_b    = (const float*)d_in[12];

  float* ws = (float*)d_ws;
  float* pdeg  = ws;  ws += (size_t)NCH * B * N;
  short* pdmsg = (short*)ws;  ws += (size_t)NCH * B * F * N / 2;  // bf16
  float* embA  = ws;  ws += (size_t)B * F * N;
  float* embB  = ws;  ws += (size_t)B * F * N;
  float* T     = ws;  ws += 2 * (size_t)B * F * N;
  short* Tbf   = (short*)ws;  ws += (size_t)B * F * N / 2;
  short* projT = (short*)ws;  ws += (size_t)B * DK * N / 2;
  float* sqnb  = ws;  ws += (size_t)B * N;
  float* ssum  = ws;  ws += 2 * (size_t)B * F;
  float* ssq   = ws;  ws += 2 * (size_t)B * F;

  constexpr int EPB = (B * F * N / 4) / 256;  // 512 blocks; block = half output row
  constexpr int AJB = MT * NCH * B;           // 512 blocks

  // ---- layer 0 ----
  k_wx<F0, false><<<dim3(N / 64, B, 4), 256, 0, stream>>>(
      emb_in, sigma, nullptr, nullptr, fst_w, fst_wres, nullptr, T, Tbf, projT, sqnb);
  k_adjmsg<<<dim3(AJB), 256, 0, stream>>>(projT, sqnb, Tbf, pdmsg, pdeg);
  k_ep<<<dim3(EPB), 256, 0, stream>>>(pdmsg, pdeg, T, fst_b, fst_bres, embA, ssum, ssq);

  // ---- layers 1..2 ----
  const float* src = embA;
  float* dst = embB;
  for (int i = 0; i < 2; ++i) {
    k_wx<F, true><<<dim3(N / 64, B, 4), 256, 0, stream>>>(
        src, nullptr, ssum, ssq, w + (size_t)i * F * 2 * F, wres + (size_t)i * F * F,
        adj_proj + (size_t)i * DK * F, T, Tbf, projT, sqnb);
    k_adjmsg<<<dim3(AJB), 256, 0, stream>>>(projT, sqnb, Tbf, pdmsg, pdeg);
    k_ep<<<dim3(EPB), 256, 0, stream>>>(pdmsg, pdeg, T, bw + (size_t)i * F,
                                        bres + (size_t)i * F, dst, ssum, ssq);
    float* tmp = (float*)src;
    src = dst;
    dst = tmp;
  }

  k_readout<<<dim3(1), 256, 0, stream>>>(ssum, fcl_w, fcl_b, (float*)d_out);
}

// Round 19
// 81.455 us; speedup vs baseline: 5.8809x; 1.0886x over previous
//
#include <hip/hip_runtime.h>
#include <hip/hip_bf16.h>
#include <math.h>

namespace {

constexpr int B  = 4;
constexpr int N  = 2048;
constexpr int F0 = 6;
constexpr int F  = 64;
constexpr int DK = 16;
constexpr float EPS = 1e-5f;
constexpr int MT   = N / 64;  // m-tiles
constexpr int NCH  = 4;       // n-chunks

typedef float fx4 __attribute__((ext_vector_type(4)));
typedef __attribute__((ext_vector_type(8)))  short bf16x8;
typedef __attribute__((ext_vector_type(4)))  short bf16x4;
typedef __attribute__((ext_vector_type(16))) float f32x16;

__device__ inline short f2bf(float x, float* xr) {
  __hip_bfloat16 h = __float2bfloat16(x);
  *xr = __bfloat162float(h);
  short s; __builtin_memcpy(&s, &h, 2);
  return s;
}
__device__ inline short f2bf(float x) {
  __hip_bfloat16 h = __float2bfloat16(x);
  short s; __builtin_memcpy(&s, &h, 2);
  return s;
}
__device__ inline float bf2f(short s) {
  unsigned int u = ((unsigned int)(unsigned short)s) << 16;
  float f; __builtin_memcpy(&f, &u, 4);
  return f;
}

// ---------------- weight-folding GEMMs -> bf16 operands for adjmsg ----------------
// z==0: Tq slice0 = bf16(W1·norm(X))   z==1: Tbf = bf16(W2·norm(X))
// z==2: Tq slice1 = bf16(Wres·norm(X)) z==3: projT = bf16(Ap·X) (B,N,DK) + sqnb
//        (layer 0: projT = bf16(X/sigma) zero-padded to DK rows)
// XBF: X buffer is bf16 (inter-layer emb); else fp32 (emb_in).
template<int FIN, bool NORM, bool XBF>
__global__ __launch_bounds__(256) void k_wx(const float* __restrict__ Xf,    // fp32 X (layer 0)
                                            const short* __restrict__ Xb,    // bf16 X (layers 1-2)
                                            const float* __restrict__ sigma, // layer0 only
                                            const float* __restrict__ ssum,  // (2*B*F) ep partials
                                            const float* __restrict__ ssq,
                                            const float* __restrict__ Wc,    // (64,2*FIN)
                                            const float* __restrict__ Wr,    // (64,FIN)
                                            const float* __restrict__ Ap,    // (DK,FIN) or null
                                            short* __restrict__ Tq,          // (B,2,64,N) bf16
                                            short* __restrict__ Tbf,         // (B,64,N) bf16
                                            short* __restrict__ projT,       // (B,N,DK) bf16
                                            float* __restrict__ sqnb) {      // (B,N)
  int z = blockIdx.z, b = blockIdx.y, n0 = blockIdx.x * 64;
  int t = threadIdx.x, n = t & 63, og = t >> 6;
  __shared__ float xS[64][FIN + 1];
  __shared__ __align__(16) float wT[FIN][68];
  __shared__ float mnS[64], rsS[64];
  __shared__ float sp[4][64];
  for (int e = t; e < FIN * 64; e += 256) {
    int f = e >> 6, nn = e & 63;
    float v = XBF ? bf2f(Xb[((size_t)b * FIN + f) * N + n0 + nn])
                  : Xf[((size_t)b * FIN + f) * N + n0 + nn];
    xS[nn][f] = v;
  }
  bool l0proj = (z == 3 && Ap == nullptr);
  if (!l0proj) {
    const float* base; int ld, off, OUT;
    if (z == 0)      { base = Wc; ld = 2 * FIN; off = 0;   OUT = 64; }
    else if (z == 1) { base = Wc; ld = 2 * FIN; off = FIN; OUT = 64; }
    else if (z == 2) { base = Wr; ld = FIN;     off = 0;   OUT = 64; }
    else             { base = Ap; ld = FIN;     off = 0;   OUT = DK; }
    for (int e = t; e < OUT * FIN; e += 256) {
      int o = e / FIN, f = e - o * FIN;
      wT[f][o] = base[(size_t)o * ld + off + f];
    }
  }
  if (NORM && z < 3 && t < 64) {  // mean/rstd from ep partial sums (2 halves/row)
    int row = b * FIN + t;
    float S = ssum[2 * row] + ssum[2 * row + 1];
    float Q = ssq[2 * row] + ssq[2 * row + 1];
    float mn = S / (float)N;
    mnS[t] = mn;
    rsS[t] = rsqrtf(Q / (float)N - mn * mn + EPS);
  }
  __syncthreads();
  if (z < 3) {
    float cacc[16] = {};
#pragma unroll 4
    for (int f = 0; f < FIN; ++f) {
      float x = xS[n][f];
      if (NORM) x = (x - mnS[f]) * rsS[f];
      fx4 w0 = *(const fx4*)&wT[f][og * 16 + 0];
      fx4 w1 = *(const fx4*)&wT[f][og * 16 + 4];
      fx4 w2 = *(const fx4*)&wT[f][og * 16 + 8];
      fx4 w3 = *(const fx4*)&wT[f][og * 16 + 12];
#pragma unroll
      for (int k = 0; k < 4; ++k) {
        cacc[k + 0]  = fmaf(w0[k], x, cacc[k + 0]);
        cacc[k + 4]  = fmaf(w1[k], x, cacc[k + 4]);
        cacc[k + 8]  = fmaf(w2[k], x, cacc[k + 8]);
        cacc[k + 12] = fmaf(w3[k], x, cacc[k + 12]);
      }
    }
    if (z == 1) {
#pragma unroll
      for (int k = 0; k < 16; ++k)
        Tbf[((size_t)b * 64 + og * 16 + k) * N + n0 + n] = f2bf(cacc[k]);
    } else {
      int sl = (z == 0) ? 0 : 1;
#pragma unroll
      for (int k = 0; k < 16; ++k)
        Tq[(((size_t)b * 2 + sl) * 64 + og * 16 + k) * N + n0 + n] = f2bf(cacc[k]);
    }
  } else {
    // proj path: 4 d-rows per thread -> bf16, n-major store (8B), + sqnorm of rounded
    float r[4];
    bf16x4 hv;
    if (Ap != nullptr) {
      float cacc[4] = {};
#pragma unroll 4
      for (int f = 0; f < FIN; ++f) {
        float x = xS[n][f];
        fx4 w0 = *(const fx4*)&wT[f][og * 4];
#pragma unroll
        for (int k = 0; k < 4; ++k) cacc[k] = fmaf(w0[k], x, cacc[k]);
      }
#pragma unroll
      for (int k = 0; k < 4; ++k) hv[k] = f2bf(cacc[k], &r[k]);
    } else {  // layer 0: scaled + zero-padded
      float inv = 1.f / sigma[0];
#pragma unroll
      for (int k = 0; k < 4; ++k) {
        int d = og * 4 + k;
        float v = (d < F0) ? xS[n][d] * inv : 0.f;
        hv[k] = f2bf(v, &r[k]);
      }
    }
    *(bf16x4*)&projT[((size_t)b * N + n0 + n) * DK + og * 4] = hv;
    float s = 0.f;
#pragma unroll
    for (int k = 0; k < 4; ++k) s = fmaf(r[k], r[k], s);
    sp[og][n] = s;
    __syncthreads();
    if (t < 64) sqnb[(size_t)b * N + n0 + t] = sp[0][t] + sp[1][t] + sp[2][t] + sp[3][t];
  }
}

// ---------------- adjacency+deg+PV via bf16 MFMA; bf16 partial outputs ----------------
__global__ __launch_bounds__(256, 4) void k_adjmsg(const short* __restrict__ projT,  // (B,N,DK)
                                                   const float* __restrict__ sqnb,
                                                   const short* __restrict__ Tbf,
                                                   short* __restrict__ pdmsg,  // (NCH,B,F,N) bf16
                                                   float* __restrict__ pdeg) { // (NCH,B,N)
  constexpr int NCb = N / NCH;      // 512
  constexpr int CPX = NCH * B / 8;  // 2 combos per XCD
  int i = blockIdx.x;
  int xcd = i & 7;
  int j = i >> 3;
  int lc = j / MT;
  int mtile = j - lc * MT;
  int combo = xcd * CPX + lc;  // bijective XCD swizzle
  int ch = combo >> 2;
  int b  = combo & 3;
  int M0 = mtile * 64;
  int n0 = ch * NCb;

  int t = threadIdx.x;
  int w = t >> 6, l = t & 63;
  int l31 = l & 31, lh = l >> 5;
  int mq = w & 1, nq = w >> 1;
  int fq = w & 1, mq2 = w >> 1;

  const short* pbT = projT + (size_t)b * N * DK;
  const short* vb = Tbf + (size_t)b * F * N;   // bf16 W2·V
  const float* sq = sqnb + (size_t)b * N;

  __shared__ __align__(16) short adjT[2][64][68];
  __shared__ __align__(16) short vS[2][64][68];
  __shared__ float sqmS[64];
  __shared__ float degS[2][64];

  // A-fragment: one dwordx4 per lane (8 consecutive shorts, n-major layout)
  int am = l31 + 32 * mq;
  bf16x8 afrag = *(const bf16x8*)&pbT[(size_t)(M0 + am) * DK + lh * 8];
  if (t < 64) sqmS[t] = sq[M0 + t];
  __syncthreads();
  float sqmr[16];
#pragma unroll
  for (int r = 0; r < 16; ++r)
    sqmr[r] = sqmS[(r & 3) + 8 * (r >> 2) + 4 * lh + 32 * mq];

  f32x16 acc;
#pragma unroll
  for (int r = 0; r < 16; ++r) acc[r] = 0.f;
  float pdm[16];
#pragma unroll
  for (int r = 0; r < 16; ++r) pdm[r] = 0.f;

  int buf = 0;
  for (int nt = 0; nt < NCb; nt += 64) {
    // B-fragment: one dwordx4 per lane + node norm
    int bn = l31 + 32 * nq;
    bf16x8 bfrag = *(const bf16x8*)&pbT[(size_t)(n0 + nt + bn) * DK + lh * 8];
    float sqn_v = sq[n0 + nt + bn];
    {  // stage V: raw bf16 copy, 32B/thread
      int f = t >> 2, nb16 = (t & 3) * 16;
#pragma unroll
      for (int jj = 0; jj < 4; ++jj) {
        *(bf16x4*)&vS[buf][f][nb16 + 4 * jj] =
            *(const bf16x4*)&vb[(size_t)f * N + n0 + nt + nb16 + 4 * jj];
      }
    }
    // gram via MFMA + exp -> adjT[buf]
    f32x16 gz;
#pragma unroll
    for (int r = 0; r < 16; ++r) gz[r] = 0.f;
    f32x16 g = __builtin_amdgcn_mfma_f32_32x32x16_bf16(afrag, bfrag, gz, 0, 0, 0);
#pragma unroll
    for (int r = 0; r < 16; ++r) {
      int m = (r & 3) + 8 * (r >> 2) + 4 * lh + 32 * mq;
      float dist = fmaxf(sqmr[r] + sqn_v - 2.f * g[r], 0.f);
      float a = __expf(-dist);
      pdm[r] += a;
      adjT[buf][m][bn] = f2bf(a);
    }
    __syncthreads();  // adjT[buf]/vS[buf] ready
    // PV via MFMA: acc[f][m] += sum_n V[f][n] * adj[m][n]
#pragma unroll
    for (int kk = 0; kk < 4; ++kk) {
      int nb = kk * 16 + lh * 8;
      int fA = l31 + 32 * fq;
      int mB = l31 + 32 * mq2;
      bf16x4 alo = *(const bf16x4*)&vS[buf][fA][nb];
      bf16x4 ahi = *(const bf16x4*)&vS[buf][fA][nb + 4];
      bf16x4 blo = *(const bf16x4*)&adjT[buf][mB][nb];
      bf16x4 bhi = *(const bf16x4*)&adjT[buf][mB][nb + 4];
      bf16x8 af2, bf2;
#pragma unroll
      for (int i2 = 0; i2 < 4; ++i2) {
        af2[i2] = alo[i2]; af2[i2 + 4] = ahi[i2];
        bf2[i2] = blo[i2]; bf2[i2 + 4] = bhi[i2];
      }
      acc = __builtin_amdgcn_mfma_f32_32x32x16_bf16(af2, bf2, acc, 0, 0, 0);
    }
    buf ^= 1;
  }
#pragma unroll
  for (int r = 0; r < 16; ++r) {
    pdm[r] += __shfl_xor(pdm[r], 1);
    pdm[r] += __shfl_xor(pdm[r], 2);
    pdm[r] += __shfl_xor(pdm[r], 4);
    pdm[r] += __shfl_xor(pdm[r], 8);
    pdm[r] += __shfl_xor(pdm[r], 16);
  }
  if (l31 == 0) {
#pragma unroll
    for (int r = 0; r < 16; ++r)
      degS[nq][(r & 3) + 8 * (r >> 2) + 4 * lh + 32 * mq] = pdm[r];
  }
  __syncthreads();
  if (t < 64) {
    float s = degS[0][t] + degS[1][t];
    __builtin_nontemporal_store(s, &pdeg[(size_t)combo * N + M0 + t]);
  }
  short* pdm_g = pdmsg + (size_t)combo * F * N;
  int m_out = l31 + 32 * mq2;
#pragma unroll
  for (int r = 0; r < 16; ++r) {
    int f_r = (r & 3) + 8 * (r >> 2) + 4 * lh + 32 * fq;
    __builtin_nontemporal_store(f2bf(acc[r]), &pdm_g[(size_t)f_r * N + M0 + m_out]);
  }
}

// ---------------- fused chunk-combine + epilogue + row-stat partials ----------------
// Writes emb as bf16; stats (ssum/ssq) computed from PRE-ROUNDING fp32 values.
__global__ __launch_bounds__(256) void k_ep(const short* __restrict__ pdmsg,  // bf16
                                            const float* __restrict__ pdeg,
                                            const short* __restrict__ Tq,     // (B,2,64,N) bf16
                                            const float* __restrict__ bias,
                                            const float* __restrict__ bres,
                                            short* __restrict__ out,          // (B,64,N) bf16
                                            float* __restrict__ ssum,   // (2*B*F)
                                            float* __restrict__ ssq) {  // (2*B*F)
  int t = threadIdx.x;
  int idx = blockIdx.x * 256 + t;  // fx4 units, total B*F*N/4
  int row = idx >> 9;              // N/4 = 512
  int c4 = idx & 511;
  int o = row & 63, b = row >> 6;
  fx4 dm = {0.f, 0.f, 0.f, 0.f};
  fx4 dg = {0.f, 0.f, 0.f, 0.f};
#pragma unroll
  for (int c = 0; c < NCH; ++c) {
    bf16x4 pv = __builtin_nontemporal_load(
        &((const bf16x4*)pdmsg)[(((size_t)c * B + b) * 64 + o) * 512 + c4]);
#pragma unroll
    for (int j = 0; j < 4; ++j) dm[j] += bf2f(pv[j]);
    dg += ((const fx4*)pdeg)[((size_t)c * B + b) * 512 + c4];
  }
  bf16x4 t0v = ((const bf16x4*)Tq)[(((size_t)b * 2 + 0) * 64 + o) * 512 + c4];
  bf16x4 t2v = ((const bf16x4*)Tq)[(((size_t)b * 2 + 1) * 64 + o) * 512 + c4];
  float bi = bias[o], br = bres[o];
  fx4 ov;
  bf16x4 ob;
#pragma unroll
  for (int j = 0; j < 4; ++j) {
    float v = fmaxf(dm[j] + bf2f(t0v[j]) * dg[j] + bi, 0.f) + bf2f(t2v[j]) + br;
    ov[j] = v;
    ob[j] = f2bf(v);
  }
  ((bf16x4*)out)[((size_t)b * 64 + o) * 512 + c4] = ob;
  float ps = ov[0] + ov[1] + ov[2] + ov[3];
  float pq = fmaf(ov[0], ov[0], fmaf(ov[1], ov[1], fmaf(ov[2], ov[2], ov[3] * ov[3])));
#pragma unroll
  for (int off = 1; off < 64; off <<= 1) {
    ps += __shfl_xor(ps, off);
    pq += __shfl_xor(pq, off);
  }
  __shared__ float r1[4], r2[4];
  if ((t & 63) == 0) { r1[t >> 6] = ps; r2[t >> 6] = pq; }
  __syncthreads();
  if (t == 0) {
    ssum[blockIdx.x] = r1[0] + r1[1] + r1[2] + r1[3];
    ssq[blockIdx.x]  = r2[0] + r2[1] + r2[2] + r2[3];
  }
}

// ---------------- readout from ep partials ----------------
__global__ __launch_bounds__(256) void k_readout(const float* __restrict__ ssum,
                                                 const float* __restrict__ fw,
                                                 const float* __restrict__ fb,
                                                 float* __restrict__ out) {
  int t = threadIdx.x, b = t >> 6, l = t & 63;
  int row = b * 64 + l;
  float po = (ssum[2 * row] + ssum[2 * row + 1]) / (float)N;
  float mn = po;
#pragma unroll
  for (int off = 1; off < 64; off <<= 1) mn += __shfl_xor(mn, off);
  mn *= (1.f / 64.f);
  float d = po - mn;
  float var = d * d;
#pragma unroll
  for (int off = 1; off < 64; off <<= 1) var += __shfl_xor(var, off);
  var *= (1.f / 64.f);
  float rs = rsqrtf(var + EPS);
  float lg = d * rs * fw[l];
#pragma unroll
  for (int off = 1; off < 64; off <<= 1) lg += __shfl_xor(lg, off);
  if (l == 0) out[b] = 1.f / (1.f + __expf(-(lg + fb[0])));
}

}  // namespace

extern "C" void kernel_launch(void* const* d_in, const int* in_sizes, int n_in,
                              void* d_out, int out_size, void* d_ws, size_t ws_size,
                              hipStream_t stream) {
  const float* emb_in   = (const float*)d_in[0];
  const float* sigma    = (const float*)d_in[1];
  const float* fst_w    = (const float*)d_in[2];
  const float* fst_b    = (const float*)d_in[3];
  const float* fst_wres = (const float*)d_in[4];
  const float* fst_bres = (const float*)d_in[5];
  const float* adj_proj = (const float*)d_in[6];
  const float* w        = (const float*)d_in[7];
  const float* bw       = (const float*)d_in[8];
  const float* wres     = (const float*)d_in[9];
  const float* bres     = (const float*)d_in[10];
  const float* fcl_w    = (const float*)d_in[11];
  const float* fcl_b    = (const float*)d_in[12];

  float* ws = (float*)d_ws;
  float* pdeg  = ws;  ws += (size_t)NCH * B * N;
  short* pdmsg = (short*)ws;  ws += (size_t)NCH * B * F * N / 2;  // bf16
  short* embA  = (short*)ws;  ws += (size_t)B * F * N / 2;        // bf16
  short* embB  = (short*)ws;  ws += (size_t)B * F * N / 2;        // bf16
  short* Tq    = (short*)ws;  ws += (size_t)B * F * N;            // 2 slices bf16
  short* Tbf   = (short*)ws;  ws += (size_t)B * F * N / 2;
  short* projT = (short*)ws;  ws += (size_t)B * DK * N / 2;
  float* sqnb  = ws;  ws += (size_t)B * N;
  float* ssum  = ws;  ws += 2 * (size_t)B * F;
  float* ssq   = ws;  ws += 2 * (size_t)B * F;

  constexpr int EPB = (B * F * N / 4) / 256;  // 512 blocks; block = half output row
  constexpr int AJB = MT * NCH * B;           // 512 blocks

  // ---- layer 0 ----
  k_wx<F0, false, false><<<dim3(N / 64, B, 4), 256, 0, stream>>>(
      emb_in, nullptr, sigma, nullptr, nullptr, fst_w, fst_wres, nullptr,
      Tq, Tbf, projT, sqnb);
  k_adjmsg<<<dim3(AJB), 256, 0, stream>>>(projT, sqnb, Tbf, pdmsg, pdeg);
  k_ep<<<dim3(EPB), 256, 0, stream>>>(pdmsg, pdeg, Tq, fst_b, fst_bres, embA, ssum, ssq);

  // ---- layers 1..2 ----
  const short* src = embA;
  short* dst = embB;
  for (int i = 0; i < 2; ++i) {
    k_wx<F, true, true><<<dim3(N / 64, B, 4), 256, 0, stream>>>(
        nullptr, src, nullptr, ssum, ssq, w + (size_t)i * F * 2 * F,
        wres + (size_t)i * F * F, adj_proj + (size_t)i * DK * F,
        Tq, Tbf, projT, sqnb);
    k_adjmsg<<<dim3(AJB), 256, 0, stream>>>(projT, sqnb, Tbf, pdmsg, pdeg);
    k_ep<<<dim3(EPB), 256, 0, stream>>>(pdmsg, pdeg, Tq, bw + (size_t)i * F,
                                        bres + (size_t)i * F, dst, ssum, ssq);
    short* tmp = (short*)src;
    src = dst;
    dst = tmp;
  }

  k_readout<<<dim3(1), 256, 0, stream>>>(ssum, fcl_w, fcl_b, (float*)d_out);
}

// Round 20
// 81.306 us; speedup vs baseline: 5.8917x; 1.0018x over previous
//
#include <hip/hip_runtime.h>
#include <hip/hip_bf16.h>
#include <math.h>

namespace {

constexpr int B  = 4;
constexpr int N  = 2048;
constexpr int F0 = 6;
constexpr int F  = 64;
constexpr int DK = 16;
constexpr float EPS = 1e-5f;
constexpr int MT   = N / 64;  // m-tiles
constexpr int NCH  = 4;       // n-chunks

typedef float fx4 __attribute__((ext_vector_type(4)));
typedef __attribute__((ext_vector_type(8)))  short bf16x8;
typedef __attribute__((ext_vector_type(4)))  short bf16x4;
typedef __attribute__((ext_vector_type(16))) float f32x16;

__device__ inline short f2bf(float x, float* xr) {
  __hip_bfloat16 h = __float2bfloat16(x);
  *xr = __bfloat162float(h);
  short s; __builtin_memcpy(&s, &h, 2);
  return s;
}
__device__ inline short f2bf(float x) {
  __hip_bfloat16 h = __float2bfloat16(x);
  short s; __builtin_memcpy(&s, &h, 2);
  return s;
}
__device__ inline float bf2f(short s) {
  unsigned int u = ((unsigned int)(unsigned short)s) << 16;
  float f; __builtin_memcpy(&f, &u, 4);
  return f;
}

// ---------------- weight-folding GEMMs -> bf16 operands ----------------
// z==0: Tq slice0 = bf16(W1·norm(X)) AND Tq slice1 = bf16(Wres·norm(X))  [merged]
// z==1: Tbf = bf16(W2·norm(X))
// z==2: projT = bf16(Ap·X) (B,N,DK) + sqnb  (layer 0: bf16(X/sigma), padded)
template<int FIN, bool NORM, bool XBF>
__global__ __launch_bounds__(256) void k_wx(const float* __restrict__ Xf,    // fp32 X (layer 0)
                                            const short* __restrict__ Xb,    // bf16 X (layers 1-2)
                                            const float* __restrict__ sigma, // layer0 only
                                            const float* __restrict__ ssum,  // (B*F) row sums
                                            const float* __restrict__ ssq,
                                            const float* __restrict__ Wc,    // (64,2*FIN)
                                            const float* __restrict__ Wr,    // (64,FIN)
                                            const float* __restrict__ Ap,    // (DK,FIN) or null
                                            short* __restrict__ Tq,          // (B,2,64,N) bf16
                                            short* __restrict__ Tbf,         // (B,64,N) bf16
                                            short* __restrict__ projT,       // (B,N,DK) bf16
                                            float* __restrict__ sqnb) {      // (B,N)
  int z = blockIdx.z, b = blockIdx.y, n0 = blockIdx.x * 64;
  int t = threadIdx.x, n = t & 63, og = t >> 6;
  __shared__ float xS[64][FIN + 1];
  __shared__ __align__(16) float wT[FIN][136];  // z0: [0..63]=W1, [64..127]=Wres
  __shared__ float mnS[64], rsS[64];
  __shared__ float sp[4][64];
  for (int e = t; e < FIN * 64; e += 256) {
    int f = e >> 6, nn = e & 63;
    float v = XBF ? bf2f(Xb[((size_t)b * FIN + f) * N + n0 + nn])
                  : Xf[((size_t)b * FIN + f) * N + n0 + nn];
    xS[nn][f] = v;
  }
  bool l0proj = (z == 2 && Ap == nullptr);
  if (z == 0) {
    for (int e = t; e < 64 * FIN; e += 256) {
      int o = e / FIN, f = e - o * FIN;
      wT[f][o] = Wc[(size_t)o * 2 * FIN + f];
      wT[f][64 + o] = Wr[(size_t)o * FIN + f];
    }
  } else if (z == 1) {
    for (int e = t; e < 64 * FIN; e += 256) {
      int o = e / FIN, f = e - o * FIN;
      wT[f][o] = Wc[(size_t)o * 2 * FIN + FIN + f];
    }
  } else if (!l0proj) {
    for (int e = t; e < DK * FIN; e += 256) {
      int o = e / FIN, f = e - o * FIN;
      wT[f][o] = Ap[(size_t)o * FIN + f];
    }
  }
  if (NORM && z < 2 && t < 64) {  // mean/rstd from ep full-row sums
    int row = b * FIN + t;
    float S = ssum[row];
    float Q = ssq[row];
    float mn = S / (float)N;
    mnS[t] = mn;
    rsS[t] = rsqrtf(Q / (float)N - mn * mn + EPS);
  }
  __syncthreads();
  if (z == 0) {
    float c1[16] = {}, c2[16] = {};
#pragma unroll 4
    for (int f = 0; f < FIN; ++f) {
      float x = xS[n][f];
      if (NORM) x = (x - mnS[f]) * rsS[f];
      fx4 w0 = *(const fx4*)&wT[f][og * 16 + 0];
      fx4 w1 = *(const fx4*)&wT[f][og * 16 + 4];
      fx4 w2 = *(const fx4*)&wT[f][og * 16 + 8];
      fx4 w3 = *(const fx4*)&wT[f][og * 16 + 12];
      fx4 u0 = *(const fx4*)&wT[f][64 + og * 16 + 0];
      fx4 u1 = *(const fx4*)&wT[f][64 + og * 16 + 4];
      fx4 u2 = *(const fx4*)&wT[f][64 + og * 16 + 8];
      fx4 u3 = *(const fx4*)&wT[f][64 + og * 16 + 12];
#pragma unroll
      for (int k = 0; k < 4; ++k) {
        c1[k + 0]  = fmaf(w0[k], x, c1[k + 0]);
        c1[k + 4]  = fmaf(w1[k], x, c1[k + 4]);
        c1[k + 8]  = fmaf(w2[k], x, c1[k + 8]);
        c1[k + 12] = fmaf(w3[k], x, c1[k + 12]);
        c2[k + 0]  = fmaf(u0[k], x, c2[k + 0]);
        c2[k + 4]  = fmaf(u1[k], x, c2[k + 4]);
        c2[k + 8]  = fmaf(u2[k], x, c2[k + 8]);
        c2[k + 12] = fmaf(u3[k], x, c2[k + 12]);
      }
    }
#pragma unroll
    for (int k = 0; k < 16; ++k) {
      Tq[(((size_t)b * 2 + 0) * 64 + og * 16 + k) * N + n0 + n] = f2bf(c1[k]);
      Tq[(((size_t)b * 2 + 1) * 64 + og * 16 + k) * N + n0 + n] = f2bf(c2[k]);
    }
  } else if (z == 1) {
    float cacc[16] = {};
#pragma unroll 4
    for (int f = 0; f < FIN; ++f) {
      float x = xS[n][f];
      if (NORM) x = (x - mnS[f]) * rsS[f];
      fx4 w0 = *(const fx4*)&wT[f][og * 16 + 0];
      fx4 w1 = *(const fx4*)&wT[f][og * 16 + 4];
      fx4 w2 = *(const fx4*)&wT[f][og * 16 + 8];
      fx4 w3 = *(const fx4*)&wT[f][og * 16 + 12];
#pragma unroll
      for (int k = 0; k < 4; ++k) {
        cacc[k + 0]  = fmaf(w0[k], x, cacc[k + 0]);
        cacc[k + 4]  = fmaf(w1[k], x, cacc[k + 4]);
        cacc[k + 8]  = fmaf(w2[k], x, cacc[k + 8]);
        cacc[k + 12] = fmaf(w3[k], x, cacc[k + 12]);
      }
    }
#pragma unroll
    for (int k = 0; k < 16; ++k)
      Tbf[((size_t)b * 64 + og * 16 + k) * N + n0 + n] = f2bf(cacc[k]);
  } else {
    // proj path: 4 d-rows per thread -> bf16, n-major store (8B), + sqnorm of rounded
    float r[4];
    bf16x4 hv;
    if (Ap != nullptr) {
      float cacc[4] = {};
#pragma unroll 4
      for (int f = 0; f < FIN; ++f) {
        float x = xS[n][f];
        fx4 w0 = *(const fx4*)&wT[f][og * 4];
#pragma unroll
        for (int k = 0; k < 4; ++k) cacc[k] = fmaf(w0[k], x, cacc[k]);
      }
#pragma unroll
      for (int k = 0; k < 4; ++k) hv[k] = f2bf(cacc[k], &r[k]);
    } else {  // layer 0: scaled + zero-padded
      float inv = 1.f / sigma[0];
#pragma unroll
      for (int k = 0; k < 4; ++k) {
        int d = og * 4 + k;
        float v = (d < F0) ? xS[n][d] * inv : 0.f;
        hv[k] = f2bf(v, &r[k]);
      }
    }
    *(bf16x4*)&projT[((size_t)b * N + n0 + n) * DK + og * 4] = hv;
    float s = 0.f;
#pragma unroll
    for (int k = 0; k < 4; ++k) s = fmaf(r[k], r[k], s);
    sp[og][n] = s;
    __syncthreads();
    if (t < 64) sqnb[(size_t)b * N + n0 + t] = sp[0][t] + sp[1][t] + sp[2][t] + sp[3][t];
  }
}

// ---------------- adjacency+deg+PV via bf16 MFMA; prefetched operands ----------------
__global__ __launch_bounds__(256, 4) void k_adjmsg(const short* __restrict__ projT,  // (B,N,DK)
                                                   const float* __restrict__ sqnb,
                                                   const short* __restrict__ Tbf,
                                                   short* __restrict__ pdmsg,  // (NCH,B,F,N) bf16
                                                   float* __restrict__ pdeg) { // (NCH,B,N)
  constexpr int NCb = N / NCH;      // 512
  constexpr int CPX = NCH * B / 8;  // 2 combos per XCD
  int i = blockIdx.x;
  int xcd = i & 7;
  int j = i >> 3;
  int lc = j / MT;
  int mtile = j - lc * MT;
  int combo = xcd * CPX + lc;  // bijective XCD swizzle
  int ch = combo >> 2;
  int b  = combo & 3;
  int M0 = mtile * 64;
  int n0 = ch * NCb;

  int t = threadIdx.x;
  int w = t >> 6, l = t & 63;
  int l31 = l & 31, lh = l >> 5;
  int mq = w & 1, nq = w >> 1;
  int fq = w & 1, mq2 = w >> 1;

  const short* pbT = projT + (size_t)b * N * DK;
  const short* vb = Tbf + (size_t)b * F * N;   // bf16 W2·V
  const float* sq = sqnb + (size_t)b * N;

  __shared__ __align__(16) short adjT[2][64][68];
  __shared__ __align__(16) short vS[2][64][68];
  __shared__ float sqmS[64];
  __shared__ float degS[2][64];

  // A-fragment: one dwordx4 per lane
  int am = l31 + 32 * mq;
  bf16x8 afrag = *(const bf16x8*)&pbT[(size_t)(M0 + am) * DK + lh * 8];
  if (t < 64) sqmS[t] = sq[M0 + t];
  __syncthreads();
  float sqmr[16];
#pragma unroll
  for (int r = 0; r < 16; ++r)
    sqmr[r] = sqmS[(r & 3) + 8 * (r >> 2) + 4 * lh + 32 * mq];

  f32x16 acc;
#pragma unroll
  for (int r = 0; r < 16; ++r) acc[r] = 0.f;
  float pdm[16];
#pragma unroll
  for (int r = 0; r < 16; ++r) pdm[r] = 0.f;

  // prefetch iteration 0 operands
  int bn = l31 + 32 * nq;
  int fV = t >> 2, nb16 = (t & 3) * 16;
  bf16x8 bfrag = *(const bf16x8*)&pbT[(size_t)(n0 + bn) * DK + lh * 8];
  float sqn_v = sq[n0 + bn];
  bf16x4 vreg[4];
#pragma unroll
  for (int jj = 0; jj < 4; ++jj)
    vreg[jj] = *(const bf16x4*)&vb[(size_t)fV * N + n0 + nb16 + 4 * jj];

  int buf = 0;
  for (int nt = 0; nt < NCb; nt += 64) {
    // commit staged V regs to LDS
#pragma unroll
    for (int jj = 0; jj < 4; ++jj)
      *(bf16x4*)&vS[buf][fV][nb16 + 4 * jj] = vreg[jj];
    // gram via MFMA + exp -> adjT[buf]
    f32x16 gz;
#pragma unroll
    for (int r = 0; r < 16; ++r) gz[r] = 0.f;
    f32x16 g = __builtin_amdgcn_mfma_f32_32x32x16_bf16(afrag, bfrag, gz, 0, 0, 0);
#pragma unroll
    for (int r = 0; r < 16; ++r) {
      int m = (r & 3) + 8 * (r >> 2) + 4 * lh + 32 * mq;
      float dist = fmaxf(sqmr[r] + sqn_v - 2.f * g[r], 0.f);
      float a = __expf(-dist);
      pdm[r] += a;
      adjT[buf][m][bn] = f2bf(a);
    }
    // prefetch next iteration's B-fragment + V tile (hidden under PV MFMAs)
    if (nt + 64 < NCb) {
      bfrag = *(const bf16x8*)&pbT[(size_t)(n0 + nt + 64 + bn) * DK + lh * 8];
      sqn_v = sq[n0 + nt + 64 + bn];
#pragma unroll
      for (int jj = 0; jj < 4; ++jj)
        vreg[jj] = *(const bf16x4*)&vb[(size_t)fV * N + n0 + nt + 64 + nb16 + 4 * jj];
    }
    __syncthreads();  // adjT[buf]/vS[buf] ready
    // PV via MFMA: acc[f][m] += sum_n V[f][n] * adj[m][n]
#pragma unroll
    for (int kk = 0; kk < 4; ++kk) {
      int nb = kk * 16 + lh * 8;
      int fA = l31 + 32 * fq;
      int mB = l31 + 32 * mq2;
      bf16x4 alo = *(const bf16x4*)&vS[buf][fA][nb];
      bf16x4 ahi = *(const bf16x4*)&vS[buf][fA][nb + 4];
      bf16x4 blo = *(const bf16x4*)&adjT[buf][mB][nb];
      bf16x4 bhi = *(const bf16x4*)&adjT[buf][mB][nb + 4];
      bf16x8 af2, bf2;
#pragma unroll
      for (int i2 = 0; i2 < 4; ++i2) {
        af2[i2] = alo[i2]; af2[i2 + 4] = ahi[i2];
        bf2[i2] = blo[i2]; bf2[i2 + 4] = bhi[i2];
      }
      acc = __builtin_amdgcn_mfma_f32_32x32x16_bf16(af2, bf2, acc, 0, 0, 0);
    }
    buf ^= 1;
  }
#pragma unroll
  for (int r = 0; r < 16; ++r) {
    pdm[r] += __shfl_xor(pdm[r], 1);
    pdm[r] += __shfl_xor(pdm[r], 2);
    pdm[r] += __shfl_xor(pdm[r], 4);
    pdm[r] += __shfl_xor(pdm[r], 8);
    pdm[r] += __shfl_xor(pdm[r], 16);
  }
  if (l31 == 0) {
#pragma unroll
    for (int r = 0; r < 16; ++r)
      degS[nq][(r & 3) + 8 * (r >> 2) + 4 * lh + 32 * mq] = pdm[r];
  }
  __syncthreads();
  if (t < 64) {
    float s = degS[0][t] + degS[1][t];
    __builtin_nontemporal_store(s, &pdeg[(size_t)combo * N + M0 + t]);
  }
  short* pdm_g = pdmsg + (size_t)combo * F * N;
  int m_out = l31 + 32 * mq2;
#pragma unroll
  for (int r = 0; r < 16; ++r) {
    int f_r = (r & 3) + 8 * (r >> 2) + 4 * lh + 32 * fq;
    __builtin_nontemporal_store(f2bf(acc[r]), &pdm_g[(size_t)f_r * N + M0 + m_out]);
  }
}

// ---------------- fused chunk-combine + epilogue + full-row stats ----------------
// Block = one output row (b,o); thread handles 2 fx4. ssum/ssq = one entry per row.
__global__ __launch_bounds__(256) void k_ep(const short* __restrict__ pdmsg,  // bf16
                                            const float* __restrict__ pdeg,
                                            const short* __restrict__ Tq,     // (B,2,64,N) bf16
                                            const float* __restrict__ bias,
                                            const float* __restrict__ bres,
                                            short* __restrict__ out,          // (B,64,N) bf16
                                            float* __restrict__ ssum,   // (B*F)
                                            float* __restrict__ ssq) {  // (B*F)
  int row = blockIdx.x;            // b*64 + o
  int o = row & 63, b = row >> 6;
  int t = threadIdx.x;
  float ps = 0.f, pq = 0.f;
  float bi = bias[o], br = bres[o];
#pragma unroll
  for (int h = 0; h < 2; ++h) {
    int c4 = t + h * 256;
    fx4 dm = {0.f, 0.f, 0.f, 0.f};
    fx4 dg = {0.f, 0.f, 0.f, 0.f};
#pragma unroll
    for (int c = 0; c < NCH; ++c) {
      bf16x4 pv = __builtin_nontemporal_load(
          &((const bf16x4*)pdmsg)[(((size_t)c * B + b) * 64 + o) * 512 + c4]);
#pragma unroll
      for (int j = 0; j < 4; ++j) dm[j] += bf2f(pv[j]);
      dg += ((const fx4*)pdeg)[((size_t)c * B + b) * 512 + c4];
    }
    bf16x4 t0v = ((const bf16x4*)Tq)[(((size_t)b * 2 + 0) * 64 + o) * 512 + c4];
    bf16x4 t2v = ((const bf16x4*)Tq)[(((size_t)b * 2 + 1) * 64 + o) * 512 + c4];
    bf16x4 ob;
#pragma unroll
    for (int j = 0; j < 4; ++j) {
      float v = fmaxf(dm[j] + bf2f(t0v[j]) * dg[j] + bi, 0.f) + bf2f(t2v[j]) + br;
      ps += v;
      pq = fmaf(v, v, pq);
      ob[j] = f2bf(v);
    }
    ((bf16x4*)out)[((size_t)b * 64 + o) * 512 + c4] = ob;
  }
#pragma unroll
  for (int off = 1; off < 64; off <<= 1) {
    ps += __shfl_xor(ps, off);
    pq += __shfl_xor(pq, off);
  }
  __shared__ float r1[4], r2[4];
  if ((t & 63) == 0) { r1[t >> 6] = ps; r2[t >> 6] = pq; }
  __syncthreads();
  if (t == 0) {
    ssum[row] = r1[0] + r1[1] + r1[2] + r1[3];
    ssq[row]  = r2[0] + r2[1] + r2[2] + r2[3];
  }
}

// ---------------- readout from ep row sums ----------------
__global__ __launch_bounds__(256) void k_readout(const float* __restrict__ ssum,
                                                 const float* __restrict__ fw,
                                                 const float* __restrict__ fb,
                                                 float* __restrict__ out) {
  int t = threadIdx.x, b = t >> 6, l = t & 63;
  float po = ssum[b * 64 + l] / (float)N;
  float mn = po;
#pragma unroll
  for (int off = 1; off < 64; off <<= 1) mn += __shfl_xor(mn, off);
  mn *= (1.f / 64.f);
  float d = po - mn;
  float var = d * d;
#pragma unroll
  for (int off = 1; off < 64; off <<= 1) var += __shfl_xor(var, off);
  var *= (1.f / 64.f);
  float rs = rsqrtf(var + EPS);
  float lg = d * rs * fw[l];
#pragma unroll
  for (int off = 1; off < 64; off <<= 1) lg += __shfl_xor(lg, off);
  if (l == 0) out[b] = 1.f / (1.f + __expf(-(lg + fb[0])));
}

}  // namespace

extern "C" void kernel_launch(void* const* d_in, const int* in_sizes, int n_in,
                              void* d_out, int out_size, void* d_ws, size_t ws_size,
                              hipStream_t stream) {
  const float* emb_in   = (const float*)d_in[0];
  const float* sigma    = (const float*)d_in[1];
  const float* fst_w    = (const float*)d_in[2];
  const float* fst_b    = (const float*)d_in[3];
  const float* fst_wres = (const float*)d_in[4];
  const float* fst_bres = (const float*)d_in[5];
  const float* adj_proj = (const float*)d_in[6];
  const float* w        = (const float*)d_in[7];
  const float* bw       = (const float*)d_in[8];
  const float* wres     = (const float*)d_in[9];
  const float* bres     = (const float*)d_in[10];
  const float* fcl_w    = (const float*)d_in[11];
  const float* fcl_b    = (const float*)d_in[12];

  float* ws = (float*)d_ws;
  float* pdeg  = ws;  ws += (size_t)NCH * B * N;
  short* pdmsg = (short*)ws;  ws += (size_t)NCH * B * F * N / 2;  // bf16
  short* embA  = (short*)ws;  ws += (size_t)B * F * N / 2;        // bf16
  short* embB  = (short*)ws;  ws += (size_t)B * F * N / 2;        // bf16
  short* Tq    = (short*)ws;  ws += (size_t)B * F * N;            // 2 slices bf16
  short* Tbf   = (short*)ws;  ws += (size_t)B * F * N / 2;
  short* projT = (short*)ws;  ws += (size_t)B * DK * N / 2;
  float* sqnb  = ws;  ws += (size_t)B * N;
  float* ssum  = ws;  ws += (size_t)B * F;
  float* ssq   = ws;  ws += (size_t)B * F;

  constexpr int EPB = B * F;        // 256 blocks; block = one output row
  constexpr int AJB = MT * NCH * B; // 512 blocks

  // ---- layer 0 ----
  k_wx<F0, false, false><<<dim3(N / 64, B, 3), 256, 0, stream>>>(
      emb_in, nullptr, sigma, nullptr, nullptr, fst_w, fst_wres, nullptr,
      Tq, Tbf, projT, sqnb);
  k_adjmsg<<<dim3(AJB), 256, 0, stream>>>(projT, sqnb, Tbf, pdmsg, pdeg);
  k_ep<<<dim3(EPB), 256, 0, stream>>>(pdmsg, pdeg, Tq, fst_b, fst_bres, embA, ssum, ssq);

  // ---- layers 1..2 ----
  const short* src = embA;
  short* dst = embB;
  for (int i = 0; i < 2; ++i) {
    k_wx<F, true, true><<<dim3(N / 64, B, 3), 256, 0, stream>>>(
        nullptr, src, nullptr, ssum, ssq, w + (size_t)i * F * 2 * F,
        wres + (size_t)i * F * F, adj_proj + (size_t)i * DK * F,
        Tq, Tbf, projT, sqnb);
    k_adjmsg<<<dim3(AJB), 256, 0, stream>>>(projT, sqnb, Tbf, pdmsg, pdeg);
    k_ep<<<dim3(EPB), 256, 0, stream>>>(pdmsg, pdeg, Tq, bw + (size_t)i * F,
                                        bres + (size_t)i * F, dst, ssum, ssq);
    short* tmp = (short*)src;
    src = dst;
    dst = tmp;
  }

  k_readout<<<dim3(1), 256, 0, stream>>>(ssum, fcl_w, fcl_b, (float*)d_out);
}